// Round 14
// baseline (721.870 us; speedup 1.0000x reference)
//
#include <hip/hip_runtime.h>
#include <hip/hip_bf16.h>
#include <math.h>

#define B_   128
#define FQ_  318
#define CH0_ 109
#define NN_  1024
#define MM_  1025
#define C1_  512
#define C2_  256
#define C3_  128
#define C0P_ 128   // t0 channel padding (109 -> 128)

typedef _Float16 f16x8 __attribute__((ext_vector_type(8)));
typedef float    f32x4 __attribute__((ext_vector_type(4)));

#define GLOAD_LDS16(g, l) __builtin_amdgcn_global_load_lds( \
    (const __attribute__((address_space(1))) void*)(g),     \
    (__attribute__((address_space(3))) void*)(l), 16, 0, 0)
#define GLOAD_LDS4(g, l) __builtin_amdgcn_global_load_lds(  \
    (const __attribute__((address_space(1))) void*)(g),     \
    (__attribute__((address_space(3))) void*)(l), 4, 0, 0)

// G LDS layout: rows of 32 f16 (64 B = 4 quads of 16 B), quad-XOR swizzle.
__device__ __forceinline__ int lds_qoff(int row, int q) {
    return row * 32 + (((q ^ ((row >> 1) & 3)) & 3) << 3);
}

// ---------------------------------------------------------------------------
// Weight prep (convs): W (C_OUT, C_IN, 3) -> FRAGMENT-MAJOR split f16 h/l:
//   Wf[ch][og][lane][e],  ch = k-chunk of 32, og = 16-row o-group,
//   lane in [0,64): row = og*16 + (lane&15), k-sub = (lane>>4)*8 + e.
// One wave B-frag load = 1 KB contiguous (lane*16B) -> perfectly coalesced.
// k-major k = kk*C_IN_PAD + c; pad region (c >= C_IN) is zero.
// ---------------------------------------------------------------------------
template <int C_IN, int C_IN_PAD, int C_OUT>
__global__ __launch_bounds__(256) void wprep_kernel(
    const float* __restrict__ W, _Float16* __restrict__ Wh, _Float16* __restrict__ Wl)
{
    constexpr int KP = 3 * C_IN_PAD;
    constexpr int OG = C_OUT / 16;
    const int id = blockIdx.x * 256 + threadIdx.x;
    if (id >= C_OUT * KP) return;
    const int e    = id & 7;
    const int l    = (id >> 3) & 63;
    const int rest = id >> 9;
    const int og   = rest % OG;
    const int ch   = rest / OG;
    const int o = og * 16 + (l & 15);
    const int k = ch * 32 + (l >> 4) * 8 + e;
    const int kk = k / C_IN_PAD, c = k - kk * C_IN_PAD;
    const float v = (c < C_IN) ? W[((size_t)o * C_IN + c) * 3 + kk] : 0.f;
    const _Float16 h = (_Float16)v;
    Wh[id] = h;
    Wl[id] = (_Float16)(v - (float)h);
}

// ---------------------------------------------------------------------------
// Weight prep (encoder): Wenc (109, 318) -> padded (128, 320) h/l f16.
// (k-major layout; encoder still stages via gload_lds + swizzle.)
// ---------------------------------------------------------------------------
__global__ __launch_bounds__(256) void wprep_enc_kernel(
    const float* __restrict__ We, _Float16* __restrict__ Wh, _Float16* __restrict__ Wl)
{
    const int id = blockIdx.x * 256 + threadIdx.x;
    if (id >= 128 * 320) return;
    const int c = id / 320, f = id - c * 320;
    const float v = (c < CH0_ && f < FQ_) ? We[(size_t)c * FQ_ + f] : 0.f;
    const _Float16 h = (_Float16)v;
    Wh[id] = h;
    Wl[id] = (_Float16)(v - (float)h);
}

// ---------------------------------------------------------------------------
// MFMA encoder (round-8 verified): t0[b, vm+1, c] = x @ We^T + benc; row 0 = 0.
// ---------------------------------------------------------------------------
__global__ __launch_bounds__(512, 2) void enc_mfma_kernel(
    const float* __restrict__ x,
    const _Float16* __restrict__ Weh, const _Float16* __restrict__ Wel,
    const float* __restrict__ benc, float* __restrict__ t0)
{
    constexpr int MROW = 264;                 // XS row stride (dwords)
    constexpr int NCE  = 10;                  // K chunks
    __shared__ __align__(16) float    XS[2][32 * MROW];
    __shared__ __align__(16) _Float16 WhS[2][128 * 32];
    __shared__ __align__(16) _Float16 WlS[2][128 * 32];

    const int tid  = threadIdx.x;
    const int lane = tid & 63, wid = tid >> 6;
    const int wr = wid >> 1, wc = wid & 1;
    const int lrow = lane & 15, lkg = lane >> 4;

    const int nwg  = 4 * B_;
    const int cpx  = nwg >> 3;
    const int swz  = (blockIdx.x & 7) * cpx + (blockIdx.x >> 3);
    const int b    = swz >> 2;
    const int mt   = swz & 3;
    const int m_base = mt * 256;

    auto stageX = [&](int ch, int buf) {
        const int f0 = ch * 32;
#pragma unroll
        for (int s = 0; s < 4; ++s) {
            const int floc = wid * 4 + s;
            int f = f0 + floc;
            if (f > FQ_ - 1) f = FQ_ - 1;
            const float* src = x + ((size_t)b * FQ_ + f) * MM_ + 1 + m_base;
            float* dst = &XS[buf][floc * MROW];
#pragma unroll
            for (int u = 0; u < 4; ++u)
                GLOAD_LDS4(src + u * 64 + lane, dst + u * 64);
        }
    };

    auto stageWE = [&](int ch, int buf) {
        const int baseRow = wid * 16;
        const int row  = baseRow + (lane >> 2);
        const int qp   = lane & 3;
        const int qsrc = qp ^ ((row >> 1) & 3);
        const size_t goff = (size_t)row * 320 + ch * 32 + qsrc * 8;
        GLOAD_LDS16(Weh + goff, &WhS[buf][baseRow * 32]);
        GLOAD_LDS16(Wel + goff, &WlS[buf][baseRow * 32]);
    };

    f32x4 acc[4][4];
#pragma unroll
    for (int i = 0; i < 4; ++i)
#pragma unroll
        for (int j = 0; j < 4; ++j) acc[i][j] = (f32x4){0.f, 0.f, 0.f, 0.f};

    auto compute = [&](int buf) {
        f16x8 ah[4], al[4];
#pragma unroll
        for (int i = 0; i < 4; ++i) {
            const int mloc = wr * 64 + i * 16 + lrow;
            const float* rp = &XS[buf][(lkg * 8) * MROW + mloc];
            f16x8 vh, vl;
#pragma unroll
            for (int j = 0; j < 8; ++j) {
                const float v = rp[j * MROW];
                const _Float16 h = (_Float16)v;
                vh[j] = h;
                vl[j] = (_Float16)(v - (float)h);
            }
            ah[i] = vh;
            al[i] = vl;
        }
        __builtin_amdgcn_s_setprio(1);
#pragma unroll
        for (int j = 0; j < 4; ++j) {
            const int cr  = wc * 64 + j * 16 + lrow;
            const int off = lds_qoff(cr, lkg);
            const f16x8 bh = *reinterpret_cast<const f16x8*>(&WhS[buf][off]);
            const f16x8 bl = *reinterpret_cast<const f16x8*>(&WlS[buf][off]);
#pragma unroll
            for (int i = 0; i < 4; ++i)
                acc[i][j] = __builtin_amdgcn_mfma_f32_16x16x32_f16(ah[i], bh, acc[i][j], 0, 0, 0);
#pragma unroll
            for (int i = 0; i < 4; ++i)
                acc[i][j] = __builtin_amdgcn_mfma_f32_16x16x32_f16(al[i], bh, acc[i][j], 0, 0, 0);
#pragma unroll
            for (int i = 0; i < 4; ++i)
                acc[i][j] = __builtin_amdgcn_mfma_f32_16x16x32_f16(ah[i], bl, acc[i][j], 0, 0, 0);
        }
        __builtin_amdgcn_s_setprio(0);
    };

    stageX(0, 0);
    stageWE(0, 0);
    __syncthreads();
    for (int ch = 0; ch < NCE; ++ch) {
        const int buf = ch & 1;
        if (ch + 1 < NCE) {
            stageX(ch + 1, buf ^ 1);
            stageWE(ch + 1, buf ^ 1);
        }
        compute(buf);
        __syncthreads();
    }

    float* outb = t0 + (size_t)b * MM_ * C0P_;
#pragma unroll
    for (int i = 0; i < 4; ++i) {
        const int vm = m_base + wr * 64 + i * 16 + lkg * 4;
#pragma unroll
        for (int j = 0; j < 4; ++j) {
            const int c = wc * 64 + j * 16 + lrow;
            const float bb = (c < CH0_) ? benc[c] : 0.f;
#pragma unroll
            for (int r = 0; r < 4; ++r) {
                const float v = (c < CH0_) ? (acc[i][j][r] + bb) : 0.f;
                outb[(size_t)(vm + r + 1) * C0P_ + c] = v;
            }
        }
    }
    if (mt == 0) {
        for (int c = tid; c < C0P_; c += 512) outb[c] = 0.f;
    }
}

// ---------------------------------------------------------------------------
// MFMA gather-conv, split-f16 3-term. R12 loop (compiler-managed waits, one
// barrier/chunk), 1024 threads = 16 waves (4n x 4o), tile 256n x OTILE,
// wave tile 64n x (OTILE/4).
// A: reg-staged gather (split once, ds_write h/l, quad-XOR swizzle) in LDS.
// W: B-fragments read DIRECTLY from global (frag-major layout, 1 KB coalesced
//    per wave) -- L1/L2-resident, decoupled from the barrier, zero LDS cost.
// out[b,n+1,o] = inv*conv(relu(g-mean)) + bias; row0=0.
// ---------------------------------------------------------------------------
template <int C_IN_STRIDE, int C_OUT, int OTILE, bool NORM>
__global__ __launch_bounds__(1024, 4) void conv_mfma_kernel(
    const float* __restrict__ tin, const int* __restrict__ idx,
    const _Float16* __restrict__ Wh, const _Float16* __restrict__ Wl,
    const float* __restrict__ bias,
    const double* __restrict__ stats_in, const int prev_count,
    double* __restrict__ stats_out, float* __restrict__ tout)
{
    constexpr int KP   = 3 * C_IN_STRIDE;
    constexpr int NC   = KP / 32;             // k-chunks
    constexpr int CPC  = C_IN_STRIDE / 32;    // chunks per child (pow2)
    constexpr int OTB  = C_OUT / OTILE;       // o-tiles
    constexpr int OF   = OTILE / 64;          // B frags per wave (o-dir)
    constexpr int OG   = C_OUT / 16;          // o-groups per chunk (W layout)
    static_assert(KP % 32 == 0 && (CPC & (CPC - 1)) == 0, "bad pad");
    static_assert(OTILE == 128 || OTILE == 256, "otile");

    __shared__ __align__(16) _Float16 GhS[2][256 * 32];
    __shared__ __align__(16) _Float16 GlS[2][256 * 32];
    __shared__ int idxs[768];
    __shared__ float s_norm[2];
    __shared__ double redS[16], redQ[16];

    const int tid = threadIdx.x;

    // XCD-aware bijective swizzle (nwg % 8 == 0 for all instantiations)
    const int nwg  = 4 * OTB * B_;
    const int cpx  = nwg >> 3;
    const int orig = blockIdx.x;
    const int swz  = (orig & 7) * cpx + (orig >> 3);
    const int b    = swz / (4 * OTB);
    const int rr   = swz - b * (4 * OTB);
    const int mt   = rr / OTB;
    const int ot   = rr - mt * OTB;
    const int n_base = mt * 256;
    const int o0     = ot * OTILE;

    if (tid < 768) {
        idxs[tid] = idx[(size_t)b * (3 * NN_) + n_base * 3 + tid];
    }
    if (NORM && tid == 0) {
        const double s = stats_in[2 * b], q = stats_in[2 * b + 1];
        const double meand = s / prev_count;
        const double var   = (q - s * s / prev_count) / (prev_count - 1);
        s_norm[0] = (float)meand;
        s_norm[1] = (float)(1.0 / (sqrt(var) + 1e-5));
    }
    __syncthreads();
    const float mean = NORM ? s_norm[0] : 0.f;
    const float inv  = NORM ? s_norm[1] : 1.f;

    const float* tb = tin + (size_t)b * MM_ * C_IN_STRIDE;
    const int gn = tid >> 2, gh = tid & 3;    // gather: 256 rows x 4 quads of 8
    const int lane = tid & 63, wid = tid >> 6;
    const int wr = wid >> 2, wc = wid & 3;    // wave grid 4n x 4o
    const int lrow = lane & 15, lkg = lane >> 4;

    float4 gv[2];

    auto load_chunk = [&](int ch) {           // 2 VMEM per thread
        const int kk = ch / CPC;
        const int c0 = (ch & (CPC - 1)) << 5;
        const int r  = idxs[gn * 3 + kk];
        const float* src = tb + (size_t)r * C_IN_STRIDE + c0 + gh * 8;
        gv[0] = *reinterpret_cast<const float4*>(src);
        gv[1] = *reinterpret_cast<const float4*>(src + 4);
    };

    auto store_chunk = [&](int buf) {
        float vv[8] = {gv[0].x, gv[0].y, gv[0].z, gv[0].w,
                       gv[1].x, gv[1].y, gv[1].z, gv[1].w};
        f16x8 vh, vl;
#pragma unroll
        for (int e = 0; e < 8; ++e) {
            float v = vv[e];
            if (NORM) v = fmaxf(0.f, v - mean);   // inv folded into epilogue
            const _Float16 h = (_Float16)v;
            vh[e] = h;
            vl[e] = (_Float16)(v - (float)h);
        }
        const int off = lds_qoff(gn, gh);
        *reinterpret_cast<f16x8*>(&GhS[buf][off]) = vh;
        *reinterpret_cast<f16x8*>(&GlS[buf][off]) = vl;
    };

    f32x4 acc[4][OF];
#pragma unroll
    for (int i = 0; i < 4; ++i)
#pragma unroll
        for (int j = 0; j < OF; ++j) acc[i][j] = (f32x4){0.f, 0.f, 0.f, 0.f};

    // this wave's B-frag base within a chunk (frag-major W layout)
    const size_t wfwave = ((size_t)(o0 >> 4) + wc * (OTILE >> 6)) * 512 + (size_t)lane * 8;

    auto compute_chunk = [&](int buf, int ch) {
        f16x8 ah[4], al[4];
#pragma unroll
        for (int f = 0; f < 4; ++f) {
            const int ar  = wr * 64 + f * 16 + lrow;
            const int off = lds_qoff(ar, lkg);
            ah[f] = *reinterpret_cast<const f16x8*>(&GhS[buf][off]);
            al[f] = *reinterpret_cast<const f16x8*>(&GlS[buf][off]);
        }
        const size_t fb = (size_t)ch * OG * 512 + wfwave;
        __builtin_amdgcn_s_setprio(1);
#pragma unroll
        for (int j = 0; j < OF; ++j) {
            const f16x8 bh = *reinterpret_cast<const f16x8*>(Wh + fb + (size_t)j * 512);
            const f16x8 bl = *reinterpret_cast<const f16x8*>(Wl + fb + (size_t)j * 512);
#pragma unroll
            for (int i = 0; i < 4; ++i)
                acc[i][j] = __builtin_amdgcn_mfma_f32_16x16x32_f16(ah[i], bh, acc[i][j], 0, 0, 0);
#pragma unroll
            for (int i = 0; i < 4; ++i)
                acc[i][j] = __builtin_amdgcn_mfma_f32_16x16x32_f16(al[i], bh, acc[i][j], 0, 0, 0);
#pragma unroll
            for (int i = 0; i < 4; ++i)
                acc[i][j] = __builtin_amdgcn_mfma_f32_16x16x32_f16(ah[i], bl, acc[i][j], 0, 0, 0);
        }
        __builtin_amdgcn_s_setprio(0);
    };

    // pipeline: dbuf LDS for A, one barrier per chunk (R8/R12-verified loop)
    load_chunk(0);
    store_chunk(0);
    __syncthreads();
    for (int ch = 0; ch < NC; ++ch) {
        const int buf = ch & 1;
        if (ch + 1 < NC) {
            load_chunk(ch + 1);          // A global -> regs (latency under MFMA)
        }
        compute_chunk(buf, ch);
        if (ch + 1 < NC) store_chunk(buf ^ 1);  // other buffer: no hazard
        __syncthreads();
    }

    // epilogue: scale by inv, add bias, store raw fp32, stats
    float bv[OF];
#pragma unroll
    for (int j = 0; j < OF; ++j) bv[j] = bias[o0 + wc * (OTILE / 4) + j * 16 + lrow];

    double s = 0.0, q = 0.0;
    float* outb = tout + (size_t)b * MM_ * C_OUT;
#pragma unroll
    for (int i = 0; i < 4; ++i) {
        const int nrow = n_base + wr * 64 + i * 16 + lkg * 4;
#pragma unroll
        for (int j = 0; j < OF; ++j) {
            const int o = o0 + wc * (OTILE / 4) + j * 16 + lrow;
#pragma unroll
            for (int r = 0; r < 4; ++r) {
                const float v = fmaf(acc[i][j][r], inv, bv[j]);
                outb[(size_t)(nrow + r + 1) * C_OUT + o] = v;
                s += (double)v;
                q += (double)v * (double)v;
            }
        }
    }
    if (mt == 0) {
        for (int o = tid; o < OTILE; o += 1024) outb[o0 + o] = 0.f;  // null row
    }

#pragma unroll
    for (int off = 32; off > 0; off >>= 1) {
        s += __shfl_down(s, off);
        q += __shfl_down(q, off);
    }
    if (lane == 0) { redS[wid] = s; redQ[wid] = q; }
    __syncthreads();
    if (tid == 0) {
        double ts = 0.0, tq = 0.0;
#pragma unroll
        for (int w = 0; w < 16; ++w) { ts += redS[w]; tq += redQ[w]; }
        atomicAdd(&stats_out[2 * b], ts);
        atomicAdd(&stats_out[2 * b + 1], tq);
    }
}

// ---------------------------------------------------------------------------
// Fused: normalize t3 on the fly, max-pool over 1025 nodes, then the MLP head.
// ---------------------------------------------------------------------------
__global__ __launch_bounds__(1024) void pool_head_kernel(
    const float* __restrict__ t3, const double* __restrict__ stats3,
    const float* __restrict__ Wh1, const float* __restrict__ bh1,
    const float* __restrict__ Wh2, const float* __restrict__ bh2,
    const float* __restrict__ Wh3, const float* __restrict__ bh3,
    const float* __restrict__ Wh4, const float* __restrict__ bh4,
    float* __restrict__ out)
{
    __shared__ float red[8][128];
    __shared__ float hs[128], h1s[128], h2s[64], h3s[32];
    const int b = blockIdx.x;
    const int o = threadIdx.x & 127, mg = threadIdx.x >> 7;

    const double ssum = stats3[2 * b], ssq = stats3[2 * b + 1];
    const double cnt  = (double)C3_ * (double)MM_;
    const double meand = ssum / cnt;
    const double var   = (ssq - ssum * ssum / cnt) / (cnt - 1.0);
    const float mean = (float)meand;
    const float inv  = (float)(1.0 / (sqrt(var) + 1e-5));

    const float* tb = t3 + (size_t)b * MM_ * C3_;
    float best = 0.f;   // relu'd values are >= 0
    for (int m = mg; m < MM_; m += 8) {
        const float v = fmaxf(0.f, (tb[(size_t)m * C3_ + o] - mean) * inv);
        best = fmaxf(best, v);
    }
    red[mg][o] = best;
    __syncthreads();

    const int t = threadIdx.x;
    if (t < 128) {
        float h = red[0][t];
#pragma unroll
        for (int g = 1; g < 8; ++g) h = fmaxf(h, red[g][t]);
        hs[t] = h;
    }
    __syncthreads();

    if (t < 128) {
        float a1 = bh1[t];
        for (int i = 0; i < 128; ++i) a1 = fmaf(Wh1[t * 128 + i], hs[i], a1);
        h1s[t] = fmaxf(a1, 0.f);
    }
    __syncthreads();

    if (t < 64) {
        float a2 = bh2[t];
        for (int i = 0; i < 128; ++i) a2 = fmaf(Wh2[t * 128 + i], h1s[i], a2);
        h2s[t] = fmaxf(a2, 0.f);
    }
    __syncthreads();

    if (t < 32) {
        float a3 = bh3[t];
        for (int i = 0; i < 64; ++i) a3 = fmaf(Wh3[t * 64 + i], h2s[i], a3);
        h3s[t] = fmaxf(a3, 0.f);
    }
    __syncthreads();

    if (t == 0) {
        float a4 = bh4[0];
        for (int i = 0; i < 32; ++i) a4 = fmaf(Wh4[i], h3s[i], a4);
        out[b] = a4;
    }
}

// ---------------------------------------------------------------------------
extern "C" void kernel_launch(void* const* d_in, const int* in_sizes, int n_in,
                              void* d_out, int out_size, void* d_ws, size_t ws_size,
                              hipStream_t stream)
{
    const float* x    = (const float*)d_in[0];
    const int*   idx  = (const int*)d_in[1];
    const float* Wenc = (const float*)d_in[2];
    const float* benc = (const float*)d_in[3];
    const float* W1   = (const float*)d_in[4];
    const float* b1   = (const float*)d_in[5];
    const float* W2   = (const float*)d_in[6];
    const float* b2   = (const float*)d_in[7];
    const float* W3   = (const float*)d_in[8];
    const float* b3   = (const float*)d_in[9];
    const float* Wh1  = (const float*)d_in[10];
    const float* bh1  = (const float*)d_in[11];
    const float* Wh2  = (const float*)d_in[12];
    const float* bh2  = (const float*)d_in[13];
    const float* Wh3  = (const float*)d_in[14];
    const float* bh3  = (const float*)d_in[15];
    const float* Wh4  = (const float*)d_in[16];
    const float* bh4  = (const float*)d_in[17];
    float* out = (float*)d_out;

    char* ws = (char*)d_ws;
    // workspace layout (bytes)
    double* stats = (double*)ws;                          // 3 x B x {sum,sumsq}
    _Float16* w1h = (_Float16*)(ws + 8192);               // 512*384*2   = 393216
    _Float16* w1l = (_Float16*)(ws + 401408);
    _Float16* w2h = (_Float16*)(ws + 794624);             // 256*1536*2  = 786432
    _Float16* w2l = (_Float16*)(ws + 1581056);
    _Float16* w3h = (_Float16*)(ws + 2367488);            // 128*768*2   = 196608
    _Float16* w3l = (_Float16*)(ws + 2564096);
    _Float16* wEh = (_Float16*)(ws + 2760704);            // 128*320*2   = 81920
    _Float16* wEl = (_Float16*)(ws + 2842624);
    const size_t offA = 2924544;                          // t0 / t2 region
    const size_t offB = offA + (size_t)B_ * MM_ * C2_ * sizeof(float);  // t1 / t3
    float* t0 = (float*)(ws + offA);                      // (B,1025,128) padded
    float* t1 = (float*)(ws + offB);
    float* t2 = (float*)(ws + offA);
    float* t3 = (float*)(ws + offB);

    hipMemsetAsync(stats, 0, 3 * B_ * 2 * sizeof(double), stream);

    wprep_kernel<CH0_, 128, C1_><<<dim3((C1_ * 384 + 255) / 256), dim3(256), 0, stream>>>(W1, w1h, w1l);
    wprep_kernel<C1_,  C1_, C2_><<<dim3((C2_ * 1536 + 255) / 256), dim3(256), 0, stream>>>(W2, w2h, w2l);
    wprep_kernel<C2_,  C2_, C3_><<<dim3((C3_ * 768 + 255) / 256), dim3(256), 0, stream>>>(W3, w3h, w3l);
    wprep_enc_kernel<<<dim3((128 * 320 + 255) / 256), dim3(256), 0, stream>>>(Wenc, wEh, wEl);

    enc_mfma_kernel<<<dim3(4 * B_), dim3(512), 0, stream>>>(x, wEh, wEl, benc, t0);

    conv_mfma_kernel<C0P_, C1_, 256, false><<<dim3(4 * 2 * B_), dim3(1024), 0, stream>>>(
        t0, idx, w1h, w1l, b1, nullptr, 1, stats + 0, t1);

    conv_mfma_kernel<C1_, C2_, 256, true><<<dim3(4 * 1 * B_), dim3(1024), 0, stream>>>(
        t1, idx, w2h, w2l, b2, stats + 0, C1_ * MM_, stats + 2 * B_, t2);

    conv_mfma_kernel<C2_, C3_, 128, true><<<dim3(4 * 1 * B_), dim3(1024), 0, stream>>>(
        t2, idx, w3h, w3l, b3, stats + 2 * B_, C2_ * MM_, stats + 4 * B_, t3);

    pool_head_kernel<<<dim3(B_), dim3(1024), 0, stream>>>(
        t3, stats + 4 * B_, Wh1, bh1, Wh2, bh2, Wh3, bh3, Wh4, bh4, out);
}

// Round 15
// 569.534 us; speedup vs baseline: 1.2675x; 1.2675x over previous
//
#include <hip/hip_runtime.h>
#include <hip/hip_bf16.h>
#include <math.h>

#define B_   128
#define FQ_  318
#define CH0_ 109
#define NN_  1024
#define MM_  1025
#define C1_  512
#define C2_  256
#define C3_  128
#define C0P_ 128   // t0 channel padding (109 -> 128)

typedef _Float16 f16x8 __attribute__((ext_vector_type(8)));
typedef float    f32x4 __attribute__((ext_vector_type(4)));

#define GLOAD_LDS16(g, l) __builtin_amdgcn_global_load_lds( \
    (const __attribute__((address_space(1))) void*)(g),     \
    (__attribute__((address_space(3))) void*)(l), 16, 0, 0)
#define GLOAD_LDS4(g, l) __builtin_amdgcn_global_load_lds(  \
    (const __attribute__((address_space(1))) void*)(g),     \
    (__attribute__((address_space(3))) void*)(l), 4, 0, 0)

// LDS rows of 32 f16 (64 B = 4 quads of 16 B), quad-XOR swizzle.
__device__ __forceinline__ int lds_qoff(int row, int q) {
    return row * 32 + (((q ^ ((row >> 1) & 3)) & 3) << 3);
}

// ---------------------------------------------------------------------------
// Weight prep (convs): W (C_OUT, C_IN, 3) -> k-major Wr[o][kk*C_IN_PAD + c],
// split fp32 into f16 hi + f16 lo. Pad region (c >= C_IN) is zero.
// (Convs now consume only Wh — 2-term split; Wl kept for layout stability.)
// ---------------------------------------------------------------------------
template <int C_IN, int C_IN_PAD, int C_OUT>
__global__ __launch_bounds__(256) void wprep_kernel(
    const float* __restrict__ W, _Float16* __restrict__ Wh, _Float16* __restrict__ Wl)
{
    constexpr int KP = 3 * C_IN_PAD;
    const int id = blockIdx.x * 256 + threadIdx.x;
    if (id >= C_OUT * KP) return;
    const int o = id / KP, k = id - o * KP;
    const int kk = k / C_IN_PAD, c = k - kk * C_IN_PAD;
    const float v = (c < C_IN) ? W[((size_t)o * C_IN + c) * 3 + kk] : 0.f;
    const _Float16 h = (_Float16)v;
    Wh[id] = h;
    Wl[id] = (_Float16)(v - (float)h);
}

// ---------------------------------------------------------------------------
// Weight prep (encoder): Wenc (109, 318) -> padded (128, 320) h/l f16.
// ---------------------------------------------------------------------------
__global__ __launch_bounds__(256) void wprep_enc_kernel(
    const float* __restrict__ We, _Float16* __restrict__ Wh, _Float16* __restrict__ Wl)
{
    const int id = blockIdx.x * 256 + threadIdx.x;
    if (id >= 128 * 320) return;
    const int c = id / 320, f = id - c * 320;
    const float v = (c < CH0_ && f < FQ_) ? We[(size_t)c * FQ_ + f] : 0.f;
    const _Float16 h = (_Float16)v;
    Wh[id] = h;
    Wl[id] = (_Float16)(v - (float)h);
}

// ---------------------------------------------------------------------------
// MFMA encoder (round-8 verified, 3-term): t0[b,vm+1,c] = x @ We^T + benc.
// ---------------------------------------------------------------------------
__global__ __launch_bounds__(512, 2) void enc_mfma_kernel(
    const float* __restrict__ x,
    const _Float16* __restrict__ Weh, const _Float16* __restrict__ Wel,
    const float* __restrict__ benc, float* __restrict__ t0)
{
    constexpr int MROW = 264;                 // XS row stride (dwords)
    constexpr int NCE  = 10;                  // K chunks
    __shared__ __align__(16) float    XS[2][32 * MROW];
    __shared__ __align__(16) _Float16 WhS[2][128 * 32];
    __shared__ __align__(16) _Float16 WlS[2][128 * 32];

    const int tid  = threadIdx.x;
    const int lane = tid & 63, wid = tid >> 6;
    const int wr = wid >> 1, wc = wid & 1;
    const int lrow = lane & 15, lkg = lane >> 4;

    const int nwg  = 4 * B_;
    const int cpx  = nwg >> 3;
    const int swz  = (blockIdx.x & 7) * cpx + (blockIdx.x >> 3);
    const int b    = swz >> 2;
    const int mt   = swz & 3;
    const int m_base = mt * 256;

    auto stageX = [&](int ch, int buf) {
        const int f0 = ch * 32;
#pragma unroll
        for (int s = 0; s < 4; ++s) {
            const int floc = wid * 4 + s;
            int f = f0 + floc;
            if (f > FQ_ - 1) f = FQ_ - 1;
            const float* src = x + ((size_t)b * FQ_ + f) * MM_ + 1 + m_base;
            float* dst = &XS[buf][floc * MROW];
#pragma unroll
            for (int u = 0; u < 4; ++u)
                GLOAD_LDS4(src + u * 64 + lane, dst + u * 64);
        }
    };

    auto stageWE = [&](int ch, int buf) {
        const int baseRow = wid * 16;
        const int row  = baseRow + (lane >> 2);
        const int qp   = lane & 3;
        const int qsrc = qp ^ ((row >> 1) & 3);
        const size_t goff = (size_t)row * 320 + ch * 32 + qsrc * 8;
        GLOAD_LDS16(Weh + goff, &WhS[buf][baseRow * 32]);
        GLOAD_LDS16(Wel + goff, &WlS[buf][baseRow * 32]);
    };

    f32x4 acc[4][4];
#pragma unroll
    for (int i = 0; i < 4; ++i)
#pragma unroll
        for (int j = 0; j < 4; ++j) acc[i][j] = (f32x4){0.f, 0.f, 0.f, 0.f};

    auto compute = [&](int buf) {
        f16x8 ah[4], al[4];
#pragma unroll
        for (int i = 0; i < 4; ++i) {
            const int mloc = wr * 64 + i * 16 + lrow;
            const float* rp = &XS[buf][(lkg * 8) * MROW + mloc];
            f16x8 vh, vl;
#pragma unroll
            for (int j = 0; j < 8; ++j) {
                const float v = rp[j * MROW];
                const _Float16 h = (_Float16)v;
                vh[j] = h;
                vl[j] = (_Float16)(v - (float)h);
            }
            ah[i] = vh;
            al[i] = vl;
        }
        __builtin_amdgcn_s_setprio(1);
#pragma unroll
        for (int j = 0; j < 4; ++j) {
            const int cr  = wc * 64 + j * 16 + lrow;
            const int off = lds_qoff(cr, lkg);
            const f16x8 bh = *reinterpret_cast<const f16x8*>(&WhS[buf][off]);
            const f16x8 bl = *reinterpret_cast<const f16x8*>(&WlS[buf][off]);
#pragma unroll
            for (int i = 0; i < 4; ++i)
                acc[i][j] = __builtin_amdgcn_mfma_f32_16x16x32_f16(ah[i], bh, acc[i][j], 0, 0, 0);
#pragma unroll
            for (int i = 0; i < 4; ++i)
                acc[i][j] = __builtin_amdgcn_mfma_f32_16x16x32_f16(al[i], bh, acc[i][j], 0, 0, 0);
#pragma unroll
            for (int i = 0; i < 4; ++i)
                acc[i][j] = __builtin_amdgcn_mfma_f32_16x16x32_f16(ah[i], bl, acc[i][j], 0, 0, 0);
        }
        __builtin_amdgcn_s_setprio(0);
    };

    stageX(0, 0);
    stageWE(0, 0);
    __syncthreads();
    for (int ch = 0; ch < NCE; ++ch) {
        const int buf = ch & 1;
        if (ch + 1 < NCE) {
            stageX(ch + 1, buf ^ 1);
            stageWE(ch + 1, buf ^ 1);
        }
        compute(buf);
        __syncthreads();
    }

    float* outb = t0 + (size_t)b * MM_ * C0P_;
#pragma unroll
    for (int i = 0; i < 4; ++i) {
        const int vm = m_base + wr * 64 + i * 16 + lkg * 4;
#pragma unroll
        for (int j = 0; j < 4; ++j) {
            const int c = wc * 64 + j * 16 + lrow;
            const float bb = (c < CH0_) ? benc[c] : 0.f;
#pragma unroll
            for (int r = 0; r < 4; ++r) {
                const float v = (c < CH0_) ? (acc[i][j][r] + bb) : 0.f;
                outb[(size_t)(vm + r + 1) * C0P_ + c] = v;
            }
        }
    }
    if (mt == 0) {
        for (int c = tid; c < C0P_; c += 512) outb[c] = 0.f;
    }
}

// ---------------------------------------------------------------------------
// MFMA gather-conv, 2-TERM split (A = f16 h+l, W = f16 h only):
//   conv(a, w) ~= ah*wh + al*wh   (rel err ~2.8e-4/layer, well under thresh)
// R12 loop (compiler-managed waits, one barrier/chunk), 1024 threads =
// 16 waves (4n x 4o), tile 256n x OTILE, wave tile 64n x (OTILE/4).
// Per wave/chunk: 32 MFMA (-33% vs 3-term), B ds_reads halved, WlS gone.
// A reg-staged (split once, ds_write h/l, quad-XOR swizzle); Wh gload_lds DMA
// (pre-swizzled source). out[b,n+1,o] = inv*conv(relu(g-mean)) + bias; row0=0.
// ---------------------------------------------------------------------------
template <int C_IN_STRIDE, int C_OUT, int OTILE, bool NORM>
__global__ __launch_bounds__(1024, 4) void conv_mfma_kernel(
    const float* __restrict__ tin, const int* __restrict__ idx,
    const _Float16* __restrict__ Wh,
    const float* __restrict__ bias,
    const double* __restrict__ stats_in, const int prev_count,
    double* __restrict__ stats_out, float* __restrict__ tout)
{
    constexpr int KP   = 3 * C_IN_STRIDE;
    constexpr int NC   = KP / 32;             // k-chunks
    constexpr int CPC  = C_IN_STRIDE / 32;    // chunks per child (pow2)
    constexpr int OTB  = C_OUT / OTILE;       // o-tiles
    constexpr int OF   = OTILE / 64;          // B frags per wave (o-dir)
    static_assert(KP % 32 == 0 && (CPC & (CPC - 1)) == 0, "bad pad");
    static_assert(OTILE == 128 || OTILE == 256, "otile");

    __shared__ __align__(16) _Float16 GhS[2][256 * 32];
    __shared__ __align__(16) _Float16 GlS[2][256 * 32];
    __shared__ __align__(16) _Float16 WhS[2][OTILE * 32];
    __shared__ int idxs[768];
    __shared__ float s_norm[2];
    __shared__ double redS[16], redQ[16];

    const int tid = threadIdx.x;

    // XCD-aware bijective swizzle (nwg % 8 == 0 for all instantiations)
    const int nwg  = 4 * OTB * B_;
    const int cpx  = nwg >> 3;
    const int orig = blockIdx.x;
    const int swz  = (orig & 7) * cpx + (orig >> 3);
    const int b    = swz / (4 * OTB);
    const int rr   = swz - b * (4 * OTB);
    const int mt   = rr / OTB;
    const int ot   = rr - mt * OTB;
    const int n_base = mt * 256;
    const int o0     = ot * OTILE;

    if (tid < 768) {
        idxs[tid] = idx[(size_t)b * (3 * NN_) + n_base * 3 + tid];
    }
    if (NORM && tid == 0) {
        const double s = stats_in[2 * b], q = stats_in[2 * b + 1];
        const double meand = s / prev_count;
        const double var   = (q - s * s / prev_count) / (prev_count - 1);
        s_norm[0] = (float)meand;
        s_norm[1] = (float)(1.0 / (sqrt(var) + 1e-5));
    }
    __syncthreads();
    const float mean = NORM ? s_norm[0] : 0.f;
    const float inv  = NORM ? s_norm[1] : 1.f;

    const float* tb = tin + (size_t)b * MM_ * C_IN_STRIDE;
    const int gn = tid >> 2, gh = tid & 3;    // gather: 256 rows x 4 quads of 8
    const int lane = tid & 63, wid = tid >> 6;
    const int wr = wid >> 2, wc = wid & 3;    // wave grid 4n x 4o
    const int lrow = lane & 15, lkg = lane >> 4;

    float4 gv[2];

    auto load_chunk = [&](int ch) {           // 2 VMEM per thread
        const int kk = ch / CPC;
        const int c0 = (ch & (CPC - 1)) << 5;
        const int r  = idxs[gn * 3 + kk];
        const float* src = tb + (size_t)r * C_IN_STRIDE + c0 + gh * 8;
        gv[0] = *reinterpret_cast<const float4*>(src);
        gv[1] = *reinterpret_cast<const float4*>(src + 4);
    };

    // Wh staging, pre-swizzled source.
    // OTILE=256: wave wid stages rows [wid*16,+16). OTILE=128: wid<8 stage.
    auto stageW = [&](int ch, int buf) {
        if constexpr (OTILE == 256) {
            const int baseRow = wid * 16;
            const int row  = baseRow + (lane >> 2);
            const int qp   = lane & 3;
            const int qsrc = qp ^ ((row >> 1) & 3);
            const size_t goff = (size_t)(o0 + row) * KP + ch * 32 + qsrc * 8;
            GLOAD_LDS16(Wh + goff, &WhS[buf][baseRow * 32]);
        } else {
            if (wid < 8) {
                const int baseRow = wid * 16;
                const int row  = baseRow + (lane >> 2);
                const int qp   = lane & 3;
                const int qsrc = qp ^ ((row >> 1) & 3);
                const size_t goff = (size_t)(o0 + row) * KP + ch * 32 + qsrc * 8;
                GLOAD_LDS16(Wh + goff, &WhS[buf][baseRow * 32]);
            }
        }
    };

    auto store_chunk = [&](int buf) {
        float vv[8] = {gv[0].x, gv[0].y, gv[0].z, gv[0].w,
                       gv[1].x, gv[1].y, gv[1].z, gv[1].w};
        f16x8 vh, vl;
#pragma unroll
        for (int e = 0; e < 8; ++e) {
            float v = vv[e];
            if (NORM) v = fmaxf(0.f, v - mean);   // inv folded into epilogue
            const _Float16 h = (_Float16)v;
            vh[e] = h;
            vl[e] = (_Float16)(v - (float)h);
        }
        const int off = lds_qoff(gn, gh);
        *reinterpret_cast<f16x8*>(&GhS[buf][off]) = vh;
        *reinterpret_cast<f16x8*>(&GlS[buf][off]) = vl;
    };

    f32x4 acc[4][OF];
#pragma unroll
    for (int i = 0; i < 4; ++i)
#pragma unroll
        for (int j = 0; j < OF; ++j) acc[i][j] = (f32x4){0.f, 0.f, 0.f, 0.f};

    auto compute_chunk = [&](int buf) {
        f16x8 ah[4], al[4];
#pragma unroll
        for (int f = 0; f < 4; ++f) {
            const int ar  = wr * 64 + f * 16 + lrow;
            const int off = lds_qoff(ar, lkg);
            ah[f] = *reinterpret_cast<const f16x8*>(&GhS[buf][off]);
            al[f] = *reinterpret_cast<const f16x8*>(&GlS[buf][off]);
        }
        __builtin_amdgcn_s_setprio(1);
#pragma unroll
        for (int j = 0; j < OF; ++j) {
            const int br  = wc * (OTILE / 4) + j * 16 + lrow;
            const int off = lds_qoff(br, lkg);
            const f16x8 bh = *reinterpret_cast<const f16x8*>(&WhS[buf][off]);
#pragma unroll
            for (int i = 0; i < 4; ++i)
                acc[i][j] = __builtin_amdgcn_mfma_f32_16x16x32_f16(ah[i], bh, acc[i][j], 0, 0, 0);
#pragma unroll
            for (int i = 0; i < 4; ++i)
                acc[i][j] = __builtin_amdgcn_mfma_f32_16x16x32_f16(al[i], bh, acc[i][j], 0, 0, 0);
        }
        __builtin_amdgcn_s_setprio(0);
    };

    // pipeline: dbuf LDS, one barrier per chunk (R8/R12-verified loop)
    stageW(0, 0);
    load_chunk(0);
    store_chunk(0);
    __syncthreads();
    for (int ch = 0; ch < NC; ++ch) {
        const int buf = ch & 1;
        if (ch + 1 < NC) {
            stageW(ch + 1, buf ^ 1);     // Wh DMA into other buffer
            load_chunk(ch + 1);          // A global -> regs (latency under MFMA)
        }
        compute_chunk(buf);
        if (ch + 1 < NC) store_chunk(buf ^ 1);  // other buffer: no hazard
        __syncthreads();
    }

    // epilogue: scale by inv, add bias, store raw fp32, stats
    float bv[OF];
#pragma unroll
    for (int j = 0; j < OF; ++j) bv[j] = bias[o0 + wc * (OTILE / 4) + j * 16 + lrow];

    double s = 0.0, q = 0.0;
    float* outb = tout + (size_t)b * MM_ * C_OUT;
#pragma unroll
    for (int i = 0; i < 4; ++i) {
        const int nrow = n_base + wr * 64 + i * 16 + lkg * 4;
#pragma unroll
        for (int j = 0; j < OF; ++j) {
            const int o = o0 + wc * (OTILE / 4) + j * 16 + lrow;
#pragma unroll
            for (int r = 0; r < 4; ++r) {
                const float v = fmaf(acc[i][j][r], inv, bv[j]);
                outb[(size_t)(nrow + r + 1) * C_OUT + o] = v;
                s += (double)v;
                q += (double)v * (double)v;
            }
        }
    }
    if (mt == 0) {
        for (int o = tid; o < OTILE; o += 1024) outb[o0 + o] = 0.f;  // null row
    }

#pragma unroll
    for (int off = 32; off > 0; off >>= 1) {
        s += __shfl_down(s, off);
        q += __shfl_down(q, off);
    }
    if (lane == 0) { redS[wid] = s; redQ[wid] = q; }
    __syncthreads();
    if (tid == 0) {
        double ts = 0.0, tq = 0.0;
#pragma unroll
        for (int w = 0; w < 16; ++w) { ts += redS[w]; tq += redQ[w]; }
        atomicAdd(&stats_out[2 * b], ts);
        atomicAdd(&stats_out[2 * b + 1], tq);
    }
}

// ---------------------------------------------------------------------------
// Fused: normalize t3 on the fly, max-pool over 1025 nodes, then the MLP head.
// ---------------------------------------------------------------------------
__global__ __launch_bounds__(1024) void pool_head_kernel(
    const float* __restrict__ t3, const double* __restrict__ stats3,
    const float* __restrict__ Wh1, const float* __restrict__ bh1,
    const float* __restrict__ Wh2, const float* __restrict__ bh2,
    const float* __restrict__ Wh3, const float* __restrict__ bh3,
    const float* __restrict__ Wh4, const float* __restrict__ bh4,
    float* __restrict__ out)
{
    __shared__ float red[8][128];
    __shared__ float hs[128], h1s[128], h2s[64], h3s[32];
    const int b = blockIdx.x;
    const int o = threadIdx.x & 127, mg = threadIdx.x >> 7;

    const double ssum = stats3[2 * b], ssq = stats3[2 * b + 1];
    const double cnt  = (double)C3_ * (double)MM_;
    const double meand = ssum / cnt;
    const double var   = (ssq - ssum * ssum / cnt) / (cnt - 1.0);
    const float mean = (float)meand;
    const float inv  = (float)(1.0 / (sqrt(var) + 1e-5));

    const float* tb = t3 + (size_t)b * MM_ * C3_;
    float best = 0.f;   // relu'd values are >= 0
    for (int m = mg; m < MM_; m += 8) {
        const float v = fmaxf(0.f, (tb[(size_t)m * C3_ + o] - mean) * inv);
        best = fmaxf(best, v);
    }
    red[mg][o] = best;
    __syncthreads();

    const int t = threadIdx.x;
    if (t < 128) {
        float h = red[0][t];
#pragma unroll
        for (int g = 1; g < 8; ++g) h = fmaxf(h, red[g][t]);
        hs[t] = h;
    }
    __syncthreads();

    if (t < 128) {
        float a1 = bh1[t];
        for (int i = 0; i < 128; ++i) a1 = fmaf(Wh1[t * 128 + i], hs[i], a1);
        h1s[t] = fmaxf(a1, 0.f);
    }
    __syncthreads();

    if (t < 64) {
        float a2 = bh2[t];
        for (int i = 0; i < 128; ++i) a2 = fmaf(Wh2[t * 128 + i], h1s[i], a2);
        h2s[t] = fmaxf(a2, 0.f);
    }
    __syncthreads();

    if (t < 32) {
        float a3 = bh3[t];
        for (int i = 0; i < 64; ++i) a3 = fmaf(Wh3[t * 64 + i], h2s[i], a3);
        h3s[t] = fmaxf(a3, 0.f);
    }
    __syncthreads();

    if (t == 0) {
        float a4 = bh4[0];
        for (int i = 0; i < 32; ++i) a4 = fmaf(Wh4[i], h3s[i], a4);
        out[b] = a4;
    }
}

// ---------------------------------------------------------------------------
extern "C" void kernel_launch(void* const* d_in, const int* in_sizes, int n_in,
                              void* d_out, int out_size, void* d_ws, size_t ws_size,
                              hipStream_t stream)
{
    const float* x    = (const float*)d_in[0];
    const int*   idx  = (const int*)d_in[1];
    const float* Wenc = (const float*)d_in[2];
    const float* benc = (const float*)d_in[3];
    const float* W1   = (const float*)d_in[4];
    const float* b1   = (const float*)d_in[5];
    const float* W2   = (const float*)d_in[6];
    const float* b2   = (const float*)d_in[7];
    const float* W3   = (const float*)d_in[8];
    const float* b3   = (const float*)d_in[9];
    const float* Wh1  = (const float*)d_in[10];
    const float* bh1  = (const float*)d_in[11];
    const float* Wh2  = (const float*)d_in[12];
    const float* bh2  = (const float*)d_in[13];
    const float* Wh3  = (const float*)d_in[14];
    const float* bh3  = (const float*)d_in[15];
    const float* Wh4  = (const float*)d_in[16];
    const float* bh4  = (const float*)d_in[17];
    float* out = (float*)d_out;

    char* ws = (char*)d_ws;
    // workspace layout (bytes)
    double* stats = (double*)ws;                          // 3 x B x {sum,sumsq}
    _Float16* w1h = (_Float16*)(ws + 8192);               // 512*384*2   = 393216
    _Float16* w1l = (_Float16*)(ws + 401408);
    _Float16* w2h = (_Float16*)(ws + 794624);             // 256*1536*2  = 786432
    _Float16* w2l = (_Float16*)(ws + 1581056);
    _Float16* w3h = (_Float16*)(ws + 2367488);            // 128*768*2   = 196608
    _Float16* w3l = (_Float16*)(ws + 2564096);
    _Float16* wEh = (_Float16*)(ws + 2760704);            // 128*320*2   = 81920
    _Float16* wEl = (_Float16*)(ws + 2842624);
    const size_t offA = 2924544;                          // t0 / t2 region
    const size_t offB = offA + (size_t)B_ * MM_ * C2_ * sizeof(float);  // t1 / t3
    float* t0 = (float*)(ws + offA);                      // (B,1025,128) padded
    float* t1 = (float*)(ws + offB);
    float* t2 = (float*)(ws + offA);
    float* t3 = (float*)(ws + offB);

    hipMemsetAsync(stats, 0, 3 * B_ * 2 * sizeof(double), stream);

    wprep_kernel<CH0_, 128, C1_><<<dim3((C1_ * 384 + 255) / 256), dim3(256), 0, stream>>>(W1, w1h, w1l);
    wprep_kernel<C1_,  C1_, C2_><<<dim3((C2_ * 1536 + 255) / 256), dim3(256), 0, stream>>>(W2, w2h, w2l);
    wprep_kernel<C2_,  C2_, C3_><<<dim3((C3_ * 768 + 255) / 256), dim3(256), 0, stream>>>(W3, w3h, w3l);
    wprep_enc_kernel<<<dim3((128 * 320 + 255) / 256), dim3(256), 0, stream>>>(Wenc, wEh, wEl);

    enc_mfma_kernel<<<dim3(4 * B_), dim3(512), 0, stream>>>(x, wEh, wEl, benc, t0);

    conv_mfma_kernel<C0P_, C1_, 256, false><<<dim3(4 * 2 * B_), dim3(1024), 0, stream>>>(
        t0, idx, w1h, b1, nullptr, 1, stats + 0, t1);

    conv_mfma_kernel<C1_, C2_, 256, true><<<dim3(4 * 1 * B_), dim3(1024), 0, stream>>>(
        t1, idx, w2h, b2, stats + 0, C1_ * MM_, stats + 2 * B_, t2);

    conv_mfma_kernel<C2_, C3_, 128, true><<<dim3(4 * 1 * B_), dim3(1024), 0, stream>>>(
        t2, idx, w3h, b3, stats + 2 * B_, C2_ * MM_, stats + 4 * B_, t3);

    pool_head_kernel<<<dim3(B_), dim3(1024), 0, stream>>>(
        t3, stats + 4 * B_, Wh1, bh1, Wh2, bh2, Wh3, bh3, Wh4, bh4, out);
}

// Round 16
// 496.586 us; speedup vs baseline: 1.4537x; 1.1469x over previous
//
#include <hip/hip_runtime.h>
#include <hip/hip_bf16.h>
#include <math.h>

#define B_   128
#define FQ_  318
#define CH0_ 109
#define NN_  1024
#define MM_  1025
#define C1_  512
#define C2_  256
#define C3_  128
#define C0P_ 128   // t0 channel padding (109 -> 128)

typedef _Float16 f16x8 __attribute__((ext_vector_type(8)));
typedef float    f32x4 __attribute__((ext_vector_type(4)));

#define GLOAD_LDS16(g, l) __builtin_amdgcn_global_load_lds( \
    (const __attribute__((address_space(1))) void*)(g),     \
    (__attribute__((address_space(3))) void*)(l), 16, 0, 0)
#define GLOAD_LDS4(g, l) __builtin_amdgcn_global_load_lds(  \
    (const __attribute__((address_space(1))) void*)(g),     \
    (__attribute__((address_space(3))) void*)(l), 4, 0, 0)

// LDS rows of 32 f16 (64 B = 4 quads of 16 B), quad-XOR swizzle.
__device__ __forceinline__ int lds_qoff(int row, int q) {
    return row * 32 + (((q ^ ((row >> 1) & 3)) & 3) << 3);
}

// ---------------------------------------------------------------------------
// Weight prep (convs): W (C_OUT, C_IN, 3) -> k-major Wr[o][kk*C_IN_PAD + c],
// split fp32 into f16 hi + f16 lo (convs consume Wh only; Wl kept for layout).
// ---------------------------------------------------------------------------
template <int C_IN, int C_IN_PAD, int C_OUT>
__global__ __launch_bounds__(256) void wprep_kernel(
    const float* __restrict__ W, _Float16* __restrict__ Wh, _Float16* __restrict__ Wl)
{
    constexpr int KP = 3 * C_IN_PAD;
    const int id = blockIdx.x * 256 + threadIdx.x;
    if (id >= C_OUT * KP) return;
    const int o = id / KP, k = id - o * KP;
    const int kk = k / C_IN_PAD, c = k - kk * C_IN_PAD;
    const float v = (c < C_IN) ? W[((size_t)o * C_IN + c) * 3 + kk] : 0.f;
    const _Float16 h = (_Float16)v;
    Wh[id] = h;
    Wl[id] = (_Float16)(v - (float)h);
}

// ---------------------------------------------------------------------------
// Weight prep (encoder): Wenc (109, 318) -> padded (128, 320) h/l f16.
// ---------------------------------------------------------------------------
__global__ __launch_bounds__(256) void wprep_enc_kernel(
    const float* __restrict__ We, _Float16* __restrict__ Wh, _Float16* __restrict__ Wl)
{
    const int id = blockIdx.x * 256 + threadIdx.x;
    if (id >= 128 * 320) return;
    const int c = id / 320, f = id - c * 320;
    const float v = (c < CH0_ && f < FQ_) ? We[(size_t)c * FQ_ + f] : 0.f;
    const _Float16 h = (_Float16)v;
    Wh[id] = h;
    Wl[id] = (_Float16)(v - (float)h);
}

// ---------------------------------------------------------------------------
// MFMA encoder (round-8 verified, 3-term): t0[b,vm+1,c] = x @ We^T + benc.
// ---------------------------------------------------------------------------
__global__ __launch_bounds__(512, 2) void enc_mfma_kernel(
    const float* __restrict__ x,
    const _Float16* __restrict__ Weh, const _Float16* __restrict__ Wel,
    const float* __restrict__ benc, float* __restrict__ t0)
{
    constexpr int MROW = 264;                 // XS row stride (dwords)
    constexpr int NCE  = 10;                  // K chunks
    __shared__ __align__(16) float    XS[2][32 * MROW];
    __shared__ __align__(16) _Float16 WhS[2][128 * 32];
    __shared__ __align__(16) _Float16 WlS[2][128 * 32];

    const int tid  = threadIdx.x;
    const int lane = tid & 63, wid = tid >> 6;
    const int wr = wid >> 1, wc = wid & 1;
    const int lrow = lane & 15, lkg = lane >> 4;

    const int nwg  = 4 * B_;
    const int cpx  = nwg >> 3;
    const int swz  = (blockIdx.x & 7) * cpx + (blockIdx.x >> 3);
    const int b    = swz >> 2;
    const int mt   = swz & 3;
    const int m_base = mt * 256;

    auto stageX = [&](int ch, int buf) {
        const int f0 = ch * 32;
#pragma unroll
        for (int s = 0; s < 4; ++s) {
            const int floc = wid * 4 + s;
            int f = f0 + floc;
            if (f > FQ_ - 1) f = FQ_ - 1;
            const float* src = x + ((size_t)b * FQ_ + f) * MM_ + 1 + m_base;
            float* dst = &XS[buf][floc * MROW];
#pragma unroll
            for (int u = 0; u < 4; ++u)
                GLOAD_LDS4(src + u * 64 + lane, dst + u * 64);
        }
    };

    auto stageWE = [&](int ch, int buf) {
        const int baseRow = wid * 16;
        const int row  = baseRow + (lane >> 2);
        const int qp   = lane & 3;
        const int qsrc = qp ^ ((row >> 1) & 3);
        const size_t goff = (size_t)row * 320 + ch * 32 + qsrc * 8;
        GLOAD_LDS16(Weh + goff, &WhS[buf][baseRow * 32]);
        GLOAD_LDS16(Wel + goff, &WlS[buf][baseRow * 32]);
    };

    f32x4 acc[4][4];
#pragma unroll
    for (int i = 0; i < 4; ++i)
#pragma unroll
        for (int j = 0; j < 4; ++j) acc[i][j] = (f32x4){0.f, 0.f, 0.f, 0.f};

    auto compute = [&](int buf) {
        f16x8 ah[4], al[4];
#pragma unroll
        for (int i = 0; i < 4; ++i) {
            const int mloc = wr * 64 + i * 16 + lrow;
            const float* rp = &XS[buf][(lkg * 8) * MROW + mloc];
            f16x8 vh, vl;
#pragma unroll
            for (int j = 0; j < 8; ++j) {
                const float v = rp[j * MROW];
                const _Float16 h = (_Float16)v;
                vh[j] = h;
                vl[j] = (_Float16)(v - (float)h);
            }
            ah[i] = vh;
            al[i] = vl;
        }
        __builtin_amdgcn_s_setprio(1);
#pragma unroll
        for (int j = 0; j < 4; ++j) {
            const int cr  = wc * 64 + j * 16 + lrow;
            const int off = lds_qoff(cr, lkg);
            const f16x8 bh = *reinterpret_cast<const f16x8*>(&WhS[buf][off]);
            const f16x8 bl = *reinterpret_cast<const f16x8*>(&WlS[buf][off]);
#pragma unroll
            for (int i = 0; i < 4; ++i)
                acc[i][j] = __builtin_amdgcn_mfma_f32_16x16x32_f16(ah[i], bh, acc[i][j], 0, 0, 0);
#pragma unroll
            for (int i = 0; i < 4; ++i)
                acc[i][j] = __builtin_amdgcn_mfma_f32_16x16x32_f16(al[i], bh, acc[i][j], 0, 0, 0);
#pragma unroll
            for (int i = 0; i < 4; ++i)
                acc[i][j] = __builtin_amdgcn_mfma_f32_16x16x32_f16(ah[i], bl, acc[i][j], 0, 0, 0);
        }
        __builtin_amdgcn_s_setprio(0);
    };

    stageX(0, 0);
    stageWE(0, 0);
    __syncthreads();
    for (int ch = 0; ch < NCE; ++ch) {
        const int buf = ch & 1;
        if (ch + 1 < NCE) {
            stageX(ch + 1, buf ^ 1);
            stageWE(ch + 1, buf ^ 1);
        }
        compute(buf);
        __syncthreads();
    }

    float* outb = t0 + (size_t)b * MM_ * C0P_;
#pragma unroll
    for (int i = 0; i < 4; ++i) {
        const int vm = m_base + wr * 64 + i * 16 + lkg * 4;
#pragma unroll
        for (int j = 0; j < 4; ++j) {
            const int c = wc * 64 + j * 16 + lrow;
            const float bb = (c < CH0_) ? benc[c] : 0.f;
#pragma unroll
            for (int r = 0; r < 4; ++r) {
                const float v = (c < CH0_) ? (acc[i][j][r] + bb) : 0.f;
                outb[(size_t)(vm + r + 1) * C0P_ + c] = v;
            }
        }
    }
    if (mt == 0) {
        for (int c = tid; c < C0P_; c += 512) outb[c] = 0.f;
    }
}

// ---------------------------------------------------------------------------
// MFMA gather-conv, PLAIN F16 (A = f16, W = f16, f32 accum):
//   16 MFMA/wave/chunk; A single-buffer-per-elem LDS; halved converts.
// R12/R15 loop (compiler-managed waits, one barrier/chunk), 1024 threads =
// 16 waves (4n x 4o), tile 256n x OTILE, wave tile 64n x (OTILE/4).
// A reg-staged (convert once, ds_write f16, quad-XOR swizzle); Wh gload_lds
// DMA (pre-swizzled). out[b,n+1,o] = inv*conv(relu(g-mean)) + bias; row0=0.
// ---------------------------------------------------------------------------
template <int C_IN_STRIDE, int C_OUT, int OTILE, bool NORM>
__global__ __launch_bounds__(1024, 4) void conv_mfma_kernel(
    const float* __restrict__ tin, const int* __restrict__ idx,
    const _Float16* __restrict__ Wh,
    const float* __restrict__ bias,
    const double* __restrict__ stats_in, const int prev_count,
    double* __restrict__ stats_out, float* __restrict__ tout)
{
    constexpr int KP   = 3 * C_IN_STRIDE;
    constexpr int NC   = KP / 32;             // k-chunks
    constexpr int CPC  = C_IN_STRIDE / 32;    // chunks per child (pow2)
    constexpr int OTB  = C_OUT / OTILE;       // o-tiles
    constexpr int OF   = OTILE / 64;          // B frags per wave (o-dir)
    static_assert(KP % 32 == 0 && (CPC & (CPC - 1)) == 0, "bad pad");
    static_assert(OTILE == 128 || OTILE == 256, "otile");

    __shared__ __align__(16) _Float16 GhS[2][256 * 32];
    __shared__ __align__(16) _Float16 WhS[2][OTILE * 32];
    __shared__ int idxs[768];
    __shared__ float s_norm[2];
    __shared__ double redS[16], redQ[16];

    const int tid = threadIdx.x;

    // XCD-aware bijective swizzle (nwg % 8 == 0 for all instantiations)
    const int nwg  = 4 * OTB * B_;
    const int cpx  = nwg >> 3;
    const int orig = blockIdx.x;
    const int swz  = (orig & 7) * cpx + (orig >> 3);
    const int b    = swz / (4 * OTB);
    const int rr   = swz - b * (4 * OTB);
    const int mt   = rr / OTB;
    const int ot   = rr - mt * OTB;
    const int n_base = mt * 256;
    const int o0     = ot * OTILE;

    if (tid < 768) {
        idxs[tid] = idx[(size_t)b * (3 * NN_) + n_base * 3 + tid];
    }
    if (NORM && tid == 0) {
        const double s = stats_in[2 * b], q = stats_in[2 * b + 1];
        const double meand = s / prev_count;
        const double var   = (q - s * s / prev_count) / (prev_count - 1);
        s_norm[0] = (float)meand;
        s_norm[1] = (float)(1.0 / (sqrt(var) + 1e-5));
    }
    __syncthreads();
    const float mean = NORM ? s_norm[0] : 0.f;
    const float inv  = NORM ? s_norm[1] : 1.f;

    const float* tb = tin + (size_t)b * MM_ * C_IN_STRIDE;
    const int gn = tid >> 2, gh = tid & 3;    // gather: 256 rows x 4 quads of 8
    const int lane = tid & 63, wid = tid >> 6;
    const int wr = wid >> 2, wc = wid & 3;    // wave grid 4n x 4o
    const int lrow = lane & 15, lkg = lane >> 4;

    float4 gv[2];

    auto load_chunk = [&](int ch) {           // 2 VMEM per thread
        const int kk = ch / CPC;
        const int c0 = (ch & (CPC - 1)) << 5;
        const int r  = idxs[gn * 3 + kk];
        const float* src = tb + (size_t)r * C_IN_STRIDE + c0 + gh * 8;
        gv[0] = *reinterpret_cast<const float4*>(src);
        gv[1] = *reinterpret_cast<const float4*>(src + 4);
    };

    // Wh staging, pre-swizzled source.
    auto stageW = [&](int ch, int buf) {
        if constexpr (OTILE == 256) {
            const int baseRow = wid * 16;
            const int row  = baseRow + (lane >> 2);
            const int qp   = lane & 3;
            const int qsrc = qp ^ ((row >> 1) & 3);
            const size_t goff = (size_t)(o0 + row) * KP + ch * 32 + qsrc * 8;
            GLOAD_LDS16(Wh + goff, &WhS[buf][baseRow * 32]);
        } else {
            if (wid < 8) {
                const int baseRow = wid * 16;
                const int row  = baseRow + (lane >> 2);
                const int qp   = lane & 3;
                const int qsrc = qp ^ ((row >> 1) & 3);
                const size_t goff = (size_t)(o0 + row) * KP + ch * 32 + qsrc * 8;
                GLOAD_LDS16(Wh + goff, &WhS[buf][baseRow * 32]);
            }
        }
    };

    auto store_chunk = [&](int buf) {
        float vv[8] = {gv[0].x, gv[0].y, gv[0].z, gv[0].w,
                       gv[1].x, gv[1].y, gv[1].z, gv[1].w};
        f16x8 vh;
#pragma unroll
        for (int e = 0; e < 8; ++e) {
            float v = vv[e];
            if (NORM) v = fmaxf(0.f, v - mean);   // inv folded into epilogue
            vh[e] = (_Float16)v;
        }
        const int off = lds_qoff(gn, gh);
        *reinterpret_cast<f16x8*>(&GhS[buf][off]) = vh;
    };

    f32x4 acc[4][OF];
#pragma unroll
    for (int i = 0; i < 4; ++i)
#pragma unroll
        for (int j = 0; j < OF; ++j) acc[i][j] = (f32x4){0.f, 0.f, 0.f, 0.f};

    auto compute_chunk = [&](int buf) {
        f16x8 ah[4];
#pragma unroll
        for (int f = 0; f < 4; ++f) {
            const int ar  = wr * 64 + f * 16 + lrow;
            const int off = lds_qoff(ar, lkg);
            ah[f] = *reinterpret_cast<const f16x8*>(&GhS[buf][off]);
        }
        __builtin_amdgcn_s_setprio(1);
#pragma unroll
        for (int j = 0; j < OF; ++j) {
            const int br  = wc * (OTILE / 4) + j * 16 + lrow;
            const int off = lds_qoff(br, lkg);
            const f16x8 bh = *reinterpret_cast<const f16x8*>(&WhS[buf][off]);
#pragma unroll
            for (int i = 0; i < 4; ++i)
                acc[i][j] = __builtin_amdgcn_mfma_f32_16x16x32_f16(ah[i], bh, acc[i][j], 0, 0, 0);
        }
        __builtin_amdgcn_s_setprio(0);
    };

    // pipeline: dbuf LDS, one barrier per chunk (R8/R12-verified loop)
    stageW(0, 0);
    load_chunk(0);
    store_chunk(0);
    __syncthreads();
    for (int ch = 0; ch < NC; ++ch) {
        const int buf = ch & 1;
        if (ch + 1 < NC) {
            stageW(ch + 1, buf ^ 1);     // Wh DMA into other buffer
            load_chunk(ch + 1);          // A global -> regs (latency under MFMA)
        }
        compute_chunk(buf);
        if (ch + 1 < NC) store_chunk(buf ^ 1);  // other buffer: no hazard
        __syncthreads();
    }

    // epilogue: scale by inv, add bias, store raw fp32, stats
    float bv[OF];
#pragma unroll
    for (int j = 0; j < OF; ++j) bv[j] = bias[o0 + wc * (OTILE / 4) + j * 16 + lrow];

    double s = 0.0, q = 0.0;
    float* outb = tout + (size_t)b * MM_ * C_OUT;
#pragma unroll
    for (int i = 0; i < 4; ++i) {
        const int nrow = n_base + wr * 64 + i * 16 + lkg * 4;
#pragma unroll
        for (int j = 0; j < OF; ++j) {
            const int o = o0 + wc * (OTILE / 4) + j * 16 + lrow;
#pragma unroll
            for (int r = 0; r < 4; ++r) {
                const float v = fmaf(acc[i][j][r], inv, bv[j]);
                outb[(size_t)(nrow + r + 1) * C_OUT + o] = v;
                s += (double)v;
                q += (double)v * (double)v;
            }
        }
    }
    if (mt == 0) {
        for (int o = tid; o < OTILE; o += 1024) outb[o0 + o] = 0.f;  // null row
    }

#pragma unroll
    for (int off = 32; off > 0; off >>= 1) {
        s += __shfl_down(s, off);
        q += __shfl_down(q, off);
    }
    if (lane == 0) { redS[wid] = s; redQ[wid] = q; }
    __syncthreads();
    if (tid == 0) {
        double ts = 0.0, tq = 0.0;
#pragma unroll
        for (int w = 0; w < 16; ++w) { ts += redS[w]; tq += redQ[w]; }
        atomicAdd(&stats_out[2 * b], ts);
        atomicAdd(&stats_out[2 * b + 1], tq);
    }
}

// ---------------------------------------------------------------------------
// Fused: normalize t3 on the fly, max-pool over 1025 nodes, then the MLP head.
// ---------------------------------------------------------------------------
__global__ __launch_bounds__(1024) void pool_head_kernel(
    const float* __restrict__ t3, const double* __restrict__ stats3,
    const float* __restrict__ Wh1, const float* __restrict__ bh1,
    const float* __restrict__ Wh2, const float* __restrict__ bh2,
    const float* __restrict__ Wh3, const float* __restrict__ bh3,
    const float* __restrict__ Wh4, const float* __restrict__ bh4,
    float* __restrict__ out)
{
    __shared__ float red[8][128];
    __shared__ float hs[128], h1s[128], h2s[64], h3s[32];
    const int b = blockIdx.x;
    const int o = threadIdx.x & 127, mg = threadIdx.x >> 7;

    const double ssum = stats3[2 * b], ssq = stats3[2 * b + 1];
    const double cnt  = (double)C3_ * (double)MM_;
    const double meand = ssum / cnt;
    const double var   = (ssq - ssum * ssum / cnt) / (cnt - 1.0);
    const float mean = (float)meand;
    const float inv  = (float)(1.0 / (sqrt(var) + 1e-5));

    const float* tb = t3 + (size_t)b * MM_ * C3_;
    float best = 0.f;   // relu'd values are >= 0
    for (int m = mg; m < MM_; m += 8) {
        const float v = fmaxf(0.f, (tb[(size_t)m * C3_ + o] - mean) * inv);
        best = fmaxf(best, v);
    }
    red[mg][o] = best;
    __syncthreads();

    const int t = threadIdx.x;
    if (t < 128) {
        float h = red[0][t];
#pragma unroll
        for (int g = 1; g < 8; ++g) h = fmaxf(h, red[g][t]);
        hs[t] = h;
    }
    __syncthreads();

    if (t < 128) {
        float a1 = bh1[t];
        for (int i = 0; i < 128; ++i) a1 = fmaf(Wh1[t * 128 + i], hs[i], a1);
        h1s[t] = fmaxf(a1, 0.f);
    }
    __syncthreads();

    if (t < 64) {
        float a2 = bh2[t];
        for (int i = 0; i < 128; ++i) a2 = fmaf(Wh2[t * 128 + i], h1s[i], a2);
        h2s[t] = fmaxf(a2, 0.f);
    }
    __syncthreads();

    if (t < 32) {
        float a3 = bh3[t];
        for (int i = 0; i < 64; ++i) a3 = fmaf(Wh3[t * 64 + i], h2s[i], a3);
        h3s[t] = fmaxf(a3, 0.f);
    }
    __syncthreads();

    if (t == 0) {
        float a4 = bh4[0];
        for (int i = 0; i < 32; ++i) a4 = fmaf(Wh4[i], h3s[i], a4);
        out[b] = a4;
    }
}

// ---------------------------------------------------------------------------
extern "C" void kernel_launch(void* const* d_in, const int* in_sizes, int n_in,
                              void* d_out, int out_size, void* d_ws, size_t ws_size,
                              hipStream_t stream)
{
    const float* x    = (const float*)d_in[0];
    const int*   idx  = (const int*)d_in[1];
    const float* Wenc = (const float*)d_in[2];
    const float* benc = (const float*)d_in[3];
    const float* W1   = (const float*)d_in[4];
    const float* b1   = (const float*)d_in[5];
    const float* W2   = (const float*)d_in[6];
    const float* b2   = (const float*)d_in[7];
    const float* W3   = (const float*)d_in[8];
    const float* b3   = (const float*)d_in[9];
    const float* Wh1  = (const float*)d_in[10];
    const float* bh1  = (const float*)d_in[11];
    const float* Wh2  = (const float*)d_in[12];
    const float* bh2  = (const float*)d_in[13];
    const float* Wh3  = (const float*)d_in[14];
    const float* bh3  = (const float*)d_in[15];
    const float* Wh4  = (const float*)d_in[16];
    const float* bh4  = (const float*)d_in[17];
    float* out = (float*)d_out;

    char* ws = (char*)d_ws;
    // workspace layout (bytes)
    double* stats = (double*)ws;                          // 3 x B x {sum,sumsq}
    _Float16* w1h = (_Float16*)(ws + 8192);               // 512*384*2   = 393216
    _Float16* w1l = (_Float16*)(ws + 401408);
    _Float16* w2h = (_Float16*)(ws + 794624);             // 256*1536*2  = 786432
    _Float16* w2l = (_Float16*)(ws + 1581056);
    _Float16* w3h = (_Float16*)(ws + 2367488);            // 128*768*2   = 196608
    _Float16* w3l = (_Float16*)(ws + 2564096);
    _Float16* wEh = (_Float16*)(ws + 2760704);            // 128*320*2   = 81920
    _Float16* wEl = (_Float16*)(ws + 2842624);
    const size_t offA = 2924544;                          // t0 / t2 region
    const size_t offB = offA + (size_t)B_ * MM_ * C2_ * sizeof(float);  // t1 / t3
    float* t0 = (float*)(ws + offA);                      // (B,1025,128) padded
    float* t1 = (float*)(ws + offB);
    float* t2 = (float*)(ws + offA);
    float* t3 = (float*)(ws + offB);

    hipMemsetAsync(stats, 0, 3 * B_ * 2 * sizeof(double), stream);

    wprep_kernel<CH0_, 128, C1_><<<dim3((C1_ * 384 + 255) / 256), dim3(256), 0, stream>>>(W1, w1h, w1l);
    wprep_kernel<C1_,  C1_, C2_><<<dim3((C2_ * 1536 + 255) / 256), dim3(256), 0, stream>>>(W2, w2h, w2l);
    wprep_kernel<C2_,  C2_, C3_><<<dim3((C3_ * 768 + 255) / 256), dim3(256), 0, stream>>>(W3, w3h, w3l);
    wprep_enc_kernel<<<dim3((128 * 320 + 255) / 256), dim3(256), 0, stream>>>(Wenc, wEh, wEl);

    enc_mfma_kernel<<<dim3(4 * B_), dim3(512), 0, stream>>>(x, wEh, wEl, benc, t0);

    conv_mfma_kernel<C0P_, C1_, 256, false><<<dim3(4 * 2 * B_), dim3(1024), 0, stream>>>(
        t0, idx, w1h, b1, nullptr, 1, stats + 0, t1);

    conv_mfma_kernel<C1_, C2_, 256, true><<<dim3(4 * 1 * B_), dim3(1024), 0, stream>>>(
        t1, idx, w2h, b2, stats + 0, C1_ * MM_, stats + 2 * B_, t2);

    conv_mfma_kernel<C2_, C3_, 128, true><<<dim3(4 * 1 * B_), dim3(1024), 0, stream>>>(
        t2, idx, w3h, b3, stats + 2 * B_, C2_ * MM_, stats + 4 * B_, t3);

    pool_head_kernel<<<dim3(B_), dim3(1024), 0, stream>>>(
        t3, stats + 4 * B_, Wh1, bh1, Wh2, bh2, Wh3, bh3, Wh4, bh4, out);
}

// Round 17
// 365.084 us; speedup vs baseline: 1.9773x; 1.3602x over previous
//
#include <hip/hip_runtime.h>
#include <hip/hip_bf16.h>
#include <math.h>

#define B_   128
#define FQ_  318
#define CH0_ 109
#define NN_  1024
#define MM_  1025
#define C1_  512
#define C2_  256
#define C3_  128
#define C0P_ 128   // t0 channel padding (109 -> 128)

typedef _Float16 f16x8 __attribute__((ext_vector_type(8)));
typedef float    f32x4 __attribute__((ext_vector_type(4)));

#define GLOAD_LDS16(g, l) __builtin_amdgcn_global_load_lds( \
    (const __attribute__((address_space(1))) void*)(g),     \
    (__attribute__((address_space(3))) void*)(l), 16, 0, 0)
#define GLOAD_LDS4(g, l) __builtin_amdgcn_global_load_lds(  \
    (const __attribute__((address_space(1))) void*)(g),     \
    (__attribute__((address_space(3))) void*)(l), 4, 0, 0)

// LDS rows of 32 f16 (64 B = 4 quads of 16 B), quad-XOR swizzle.
__device__ __forceinline__ int lds_qoff(int row, int q) {
    return row * 32 + (((q ^ ((row >> 1) & 3)) & 3) << 3);
}

// ---------------------------------------------------------------------------
// Weight prep (convs): W (C_OUT, C_IN, 3) -> k-major Wr[o][kk*C_IN_PAD + c],
// split fp32 into f16 hi + f16 lo (convs consume Wh only).
// ---------------------------------------------------------------------------
template <int C_IN, int C_IN_PAD, int C_OUT>
__global__ __launch_bounds__(256) void wprep_kernel(
    const float* __restrict__ W, _Float16* __restrict__ Wh, _Float16* __restrict__ Wl)
{
    constexpr int KP = 3 * C_IN_PAD;
    const int id = blockIdx.x * 256 + threadIdx.x;
    if (id >= C_OUT * KP) return;
    const int o = id / KP, k = id - o * KP;
    const int kk = k / C_IN_PAD, c = k - kk * C_IN_PAD;
    const float v = (c < C_IN) ? W[((size_t)o * C_IN + c) * 3 + kk] : 0.f;
    const _Float16 h = (_Float16)v;
    Wh[id] = h;
    Wl[id] = (_Float16)(v - (float)h);
}

// ---------------------------------------------------------------------------
// Weight prep (encoder): Wenc (109, 318) -> padded (128, 320) h/l f16.
// ---------------------------------------------------------------------------
__global__ __launch_bounds__(256) void wprep_enc_kernel(
    const float* __restrict__ We, _Float16* __restrict__ Wh, _Float16* __restrict__ Wl)
{
    const int id = blockIdx.x * 256 + threadIdx.x;
    if (id >= 128 * 320) return;
    const int c = id / 320, f = id - c * 320;
    const float v = (c < CH0_ && f < FQ_) ? We[(size_t)c * FQ_ + f] : 0.f;
    const _Float16 h = (_Float16)v;
    Wh[id] = h;
    Wl[id] = (_Float16)(v - (float)h);
}

// ---------------------------------------------------------------------------
// MFMA encoder (round-8 verified, 3-term): t0[b,vm+1,c] = x @ We^T + benc.
// t0 stored as f16 (conv path quantizes to f16 anyway).
// ---------------------------------------------------------------------------
__global__ __launch_bounds__(512, 2) void enc_mfma_kernel(
    const float* __restrict__ x,
    const _Float16* __restrict__ Weh, const _Float16* __restrict__ Wel,
    const float* __restrict__ benc, _Float16* __restrict__ t0)
{
    constexpr int MROW = 264;                 // XS row stride (dwords)
    constexpr int NCE  = 10;                  // K chunks
    __shared__ __align__(16) float    XS[2][32 * MROW];
    __shared__ __align__(16) _Float16 WhS[2][128 * 32];
    __shared__ __align__(16) _Float16 WlS[2][128 * 32];

    const int tid  = threadIdx.x;
    const int lane = tid & 63, wid = tid >> 6;
    const int wr = wid >> 1, wc = wid & 1;
    const int lrow = lane & 15, lkg = lane >> 4;

    const int nwg  = 4 * B_;
    const int cpx  = nwg >> 3;
    const int swz  = (blockIdx.x & 7) * cpx + (blockIdx.x >> 3);
    const int b    = swz >> 2;
    const int mt   = swz & 3;
    const int m_base = mt * 256;

    auto stageX = [&](int ch, int buf) {
        const int f0 = ch * 32;
#pragma unroll
        for (int s = 0; s < 4; ++s) {
            const int floc = wid * 4 + s;
            int f = f0 + floc;
            if (f > FQ_ - 1) f = FQ_ - 1;
            const float* src = x + ((size_t)b * FQ_ + f) * MM_ + 1 + m_base;
            float* dst = &XS[buf][floc * MROW];
#pragma unroll
            for (int u = 0; u < 4; ++u)
                GLOAD_LDS4(src + u * 64 + lane, dst + u * 64);
        }
    };

    auto stageWE = [&](int ch, int buf) {
        const int baseRow = wid * 16;
        const int row  = baseRow + (lane >> 2);
        const int qp   = lane & 3;
        const int qsrc = qp ^ ((row >> 1) & 3);
        const size_t goff = (size_t)row * 320 + ch * 32 + qsrc * 8;
        GLOAD_LDS16(Weh + goff, &WhS[buf][baseRow * 32]);
        GLOAD_LDS16(Wel + goff, &WlS[buf][baseRow * 32]);
    };

    f32x4 acc[4][4];
#pragma unroll
    for (int i = 0; i < 4; ++i)
#pragma unroll
        for (int j = 0; j < 4; ++j) acc[i][j] = (f32x4){0.f, 0.f, 0.f, 0.f};

    auto compute = [&](int buf) {
        f16x8 ah[4], al[4];
#pragma unroll
        for (int i = 0; i < 4; ++i) {
            const int mloc = wr * 64 + i * 16 + lrow;
            const float* rp = &XS[buf][(lkg * 8) * MROW + mloc];
            f16x8 vh, vl;
#pragma unroll
            for (int j = 0; j < 8; ++j) {
                const float v = rp[j * MROW];
                const _Float16 h = (_Float16)v;
                vh[j] = h;
                vl[j] = (_Float16)(v - (float)h);
            }
            ah[i] = vh;
            al[i] = vl;
        }
        __builtin_amdgcn_s_setprio(1);
#pragma unroll
        for (int j = 0; j < 4; ++j) {
            const int cr  = wc * 64 + j * 16 + lrow;
            const int off = lds_qoff(cr, lkg);
            const f16x8 bh = *reinterpret_cast<const f16x8*>(&WhS[buf][off]);
            const f16x8 bl = *reinterpret_cast<const f16x8*>(&WlS[buf][off]);
#pragma unroll
            for (int i = 0; i < 4; ++i)
                acc[i][j] = __builtin_amdgcn_mfma_f32_16x16x32_f16(ah[i], bh, acc[i][j], 0, 0, 0);
#pragma unroll
            for (int i = 0; i < 4; ++i)
                acc[i][j] = __builtin_amdgcn_mfma_f32_16x16x32_f16(al[i], bh, acc[i][j], 0, 0, 0);
#pragma unroll
            for (int i = 0; i < 4; ++i)
                acc[i][j] = __builtin_amdgcn_mfma_f32_16x16x32_f16(ah[i], bl, acc[i][j], 0, 0, 0);
        }
        __builtin_amdgcn_s_setprio(0);
    };

    stageX(0, 0);
    stageWE(0, 0);
    __syncthreads();
    for (int ch = 0; ch < NCE; ++ch) {
        const int buf = ch & 1;
        if (ch + 1 < NCE) {
            stageX(ch + 1, buf ^ 1);
            stageWE(ch + 1, buf ^ 1);
        }
        compute(buf);
        __syncthreads();
    }

    _Float16* outb = t0 + (size_t)b * MM_ * C0P_;
#pragma unroll
    for (int i = 0; i < 4; ++i) {
        const int vm = m_base + wr * 64 + i * 16 + lkg * 4;
#pragma unroll
        for (int j = 0; j < 4; ++j) {
            const int c = wc * 64 + j * 16 + lrow;
            const float bb = (c < CH0_) ? benc[c] : 0.f;
#pragma unroll
            for (int r = 0; r < 4; ++r) {
                const float v = (c < CH0_) ? (acc[i][j][r] + bb) : 0.f;
                outb[(size_t)(vm + r + 1) * C0P_ + c] = (_Float16)v;
            }
        }
    }
    if (mt == 0) {
        for (int c = tid; c < C0P_; c += 512) outb[c] = (_Float16)0.f;
    }
}

// ---------------------------------------------------------------------------
// MFMA gather-conv, plain f16 (A = f16, W = f16, f32 accum), F16 TREES:
// tin/tout are f16 -> gather is ONE 16B load per thread, HBM traffic halved.
// NORM=false: A staging is a pure byte move (no converts at all).
// R12/R16 loop (compiler-managed waits, one barrier/chunk), 1024 threads =
// 16 waves (4n x 4o), tile 256n x OTILE, wave tile 64n x (OTILE/4).
// out[b,n+1,o] = inv*conv(relu(g-mean)) + bias (stats from f32 acc); row0=0.
// ---------------------------------------------------------------------------
template <int C_IN_STRIDE, int C_OUT, int OTILE, bool NORM>
__global__ __launch_bounds__(1024, 4) void conv_mfma_kernel(
    const _Float16* __restrict__ tin, const int* __restrict__ idx,
    const _Float16* __restrict__ Wh,
    const float* __restrict__ bias,
    const double* __restrict__ stats_in, const int prev_count,
    double* __restrict__ stats_out, _Float16* __restrict__ tout)
{
    constexpr int KP   = 3 * C_IN_STRIDE;
    constexpr int NC   = KP / 32;             // k-chunks
    constexpr int CPC  = C_IN_STRIDE / 32;    // chunks per child (pow2)
    constexpr int OTB  = C_OUT / OTILE;       // o-tiles
    constexpr int OF   = OTILE / 64;          // B frags per wave (o-dir)
    static_assert(KP % 32 == 0 && (CPC & (CPC - 1)) == 0, "bad pad");
    static_assert(OTILE == 128 || OTILE == 256, "otile");

    __shared__ __align__(16) _Float16 GhS[2][256 * 32];
    __shared__ __align__(16) _Float16 WhS[2][OTILE * 32];
    __shared__ int idxs[768];
    __shared__ float s_norm[2];
    __shared__ double redS[16], redQ[16];

    const int tid = threadIdx.x;

    // XCD-aware bijective swizzle (nwg % 8 == 0 for all instantiations)
    const int nwg  = 4 * OTB * B_;
    const int cpx  = nwg >> 3;
    const int orig = blockIdx.x;
    const int swz  = (orig & 7) * cpx + (orig >> 3);
    const int b    = swz / (4 * OTB);
    const int rr   = swz - b * (4 * OTB);
    const int mt   = rr / OTB;
    const int ot   = rr - mt * OTB;
    const int n_base = mt * 256;
    const int o0     = ot * OTILE;

    if (tid < 768) {
        idxs[tid] = idx[(size_t)b * (3 * NN_) + n_base * 3 + tid];
    }
    if (NORM && tid == 0) {
        const double s = stats_in[2 * b], q = stats_in[2 * b + 1];
        const double meand = s / prev_count;
        const double var   = (q - s * s / prev_count) / (prev_count - 1);
        s_norm[0] = (float)meand;
        s_norm[1] = (float)(1.0 / (sqrt(var) + 1e-5));
    }
    __syncthreads();
    const float mean = NORM ? s_norm[0] : 0.f;
    const float inv  = NORM ? s_norm[1] : 1.f;

    const _Float16* tb = tin + (size_t)b * MM_ * C_IN_STRIDE;
    const int gn = tid >> 2, gh = tid & 3;    // gather: 256 rows x 4 quads of 8
    const int lane = tid & 63, wid = tid >> 6;
    const int wr = wid >> 2, wc = wid & 3;    // wave grid 4n x 4o
    const int lrow = lane & 15, lkg = lane >> 4;

    f16x8 gv;

    auto load_chunk = [&](int ch) {           // 1 VMEM (16 B) per thread
        const int kk = ch / CPC;
        const int c0 = (ch & (CPC - 1)) << 5;
        const int r  = idxs[gn * 3 + kk];
        gv = *reinterpret_cast<const f16x8*>(tb + (size_t)r * C_IN_STRIDE + c0 + gh * 8);
    };

    // Wh staging, pre-swizzled source.
    auto stageW = [&](int ch, int buf) {
        if constexpr (OTILE == 256) {
            const int baseRow = wid * 16;
            const int row  = baseRow + (lane >> 2);
            const int qp   = lane & 3;
            const int qsrc = qp ^ ((row >> 1) & 3);
            const size_t goff = (size_t)(o0 + row) * KP + ch * 32 + qsrc * 8;
            GLOAD_LDS16(Wh + goff, &WhS[buf][baseRow * 32]);
        } else {
            if (wid < 8) {
                const int baseRow = wid * 16;
                const int row  = baseRow + (lane >> 2);
                const int qp   = lane & 3;
                const int qsrc = qp ^ ((row >> 1) & 3);
                const size_t goff = (size_t)(o0 + row) * KP + ch * 32 + qsrc * 8;
                GLOAD_LDS16(Wh + goff, &WhS[buf][baseRow * 32]);
            }
        }
    };

    auto store_chunk = [&](int buf) {
        const int off = lds_qoff(gn, gh);
        if constexpr (!NORM) {
            *reinterpret_cast<f16x8*>(&GhS[buf][off]) = gv;   // pure byte move
        } else {
            f16x8 vh;
#pragma unroll
            for (int e = 0; e < 8; ++e) {
                float v = (float)gv[e];
                v = fmaxf(0.f, v - mean);     // inv folded into epilogue
                vh[e] = (_Float16)v;
            }
            *reinterpret_cast<f16x8*>(&GhS[buf][off]) = vh;
        }
    };

    f32x4 acc[4][OF];
#pragma unroll
    for (int i = 0; i < 4; ++i)
#pragma unroll
        for (int j = 0; j < OF; ++j) acc[i][j] = (f32x4){0.f, 0.f, 0.f, 0.f};

    auto compute_chunk = [&](int buf) {
        f16x8 ah[4];
#pragma unroll
        for (int f = 0; f < 4; ++f) {
            const int ar  = wr * 64 + f * 16 + lrow;
            const int off = lds_qoff(ar, lkg);
            ah[f] = *reinterpret_cast<const f16x8*>(&GhS[buf][off]);
        }
        __builtin_amdgcn_s_setprio(1);
#pragma unroll
        for (int j = 0; j < OF; ++j) {
            const int br  = wc * (OTILE / 4) + j * 16 + lrow;
            const int off = lds_qoff(br, lkg);
            const f16x8 bh = *reinterpret_cast<const f16x8*>(&WhS[buf][off]);
#pragma unroll
            for (int i = 0; i < 4; ++i)
                acc[i][j] = __builtin_amdgcn_mfma_f32_16x16x32_f16(ah[i], bh, acc[i][j], 0, 0, 0);
        }
        __builtin_amdgcn_s_setprio(0);
    };

    // pipeline: dbuf LDS, one barrier per chunk (R8/R12-verified loop)
    stageW(0, 0);
    load_chunk(0);
    store_chunk(0);
    __syncthreads();
    for (int ch = 0; ch < NC; ++ch) {
        const int buf = ch & 1;
        if (ch + 1 < NC) {
            stageW(ch + 1, buf ^ 1);     // Wh DMA into other buffer
            load_chunk(ch + 1);          // A gather -> regs (latency under MFMA)
        }
        compute_chunk(buf);
        if (ch + 1 < NC) store_chunk(buf ^ 1);  // other buffer: no hazard
        __syncthreads();
    }

    // epilogue: scale by inv, add bias, stats on f32, store f16
    float bv[OF];
#pragma unroll
    for (int j = 0; j < OF; ++j) bv[j] = bias[o0 + wc * (OTILE / 4) + j * 16 + lrow];

    double s = 0.0, q = 0.0;
    _Float16* outb = tout + (size_t)b * MM_ * C_OUT;
#pragma unroll
    for (int i = 0; i < 4; ++i) {
        const int nrow = n_base + wr * 64 + i * 16 + lkg * 4;
#pragma unroll
        for (int j = 0; j < OF; ++j) {
            const int o = o0 + wc * (OTILE / 4) + j * 16 + lrow;
#pragma unroll
            for (int r = 0; r < 4; ++r) {
                const float v = fmaf(acc[i][j][r], inv, bv[j]);
                outb[(size_t)(nrow + r + 1) * C_OUT + o] = (_Float16)v;
                s += (double)v;
                q += (double)v * (double)v;
            }
        }
    }
    if (mt == 0) {
        for (int o = tid; o < OTILE; o += 1024) outb[o0 + o] = (_Float16)0.f;
    }

#pragma unroll
    for (int off = 32; off > 0; off >>= 1) {
        s += __shfl_down(s, off);
        q += __shfl_down(q, off);
    }
    if (lane == 0) { redS[wid] = s; redQ[wid] = q; }
    __syncthreads();
    if (tid == 0) {
        double ts = 0.0, tq = 0.0;
#pragma unroll
        for (int w = 0; w < 16; ++w) { ts += redS[w]; tq += redQ[w]; }
        atomicAdd(&stats_out[2 * b], ts);
        atomicAdd(&stats_out[2 * b + 1], tq);
    }
}

// ---------------------------------------------------------------------------
// Fused: normalize t3 (f16) on the fly, max-pool over 1025 nodes, MLP head.
// ---------------------------------------------------------------------------
__global__ __launch_bounds__(1024) void pool_head_kernel(
    const _Float16* __restrict__ t3, const double* __restrict__ stats3,
    const float* __restrict__ Wh1, const float* __restrict__ bh1,
    const float* __restrict__ Wh2, const float* __restrict__ bh2,
    const float* __restrict__ Wh3, const float* __restrict__ bh3,
    const float* __restrict__ Wh4, const float* __restrict__ bh4,
    float* __restrict__ out)
{
    __shared__ float red[8][128];
    __shared__ float hs[128], h1s[128], h2s[64], h3s[32];
    const int b = blockIdx.x;
    const int o = threadIdx.x & 127, mg = threadIdx.x >> 7;

    const double ssum = stats3[2 * b], ssq = stats3[2 * b + 1];
    const double cnt  = (double)C3_ * (double)MM_;
    const double meand = ssum / cnt;
    const double var   = (ssq - ssum * ssum / cnt) / (cnt - 1.0);
    const float mean = (float)meand;
    const float inv  = (float)(1.0 / (sqrt(var) + 1e-5));

    const _Float16* tb = t3 + (size_t)b * MM_ * C3_;
    float best = 0.f;   // relu'd values are >= 0
    for (int m = mg; m < MM_; m += 8) {
        const float v = fmaxf(0.f, ((float)tb[(size_t)m * C3_ + o] - mean) * inv);
        best = fmaxf(best, v);
    }
    red[mg][o] = best;
    __syncthreads();

    const int t = threadIdx.x;
    if (t < 128) {
        float h = red[0][t];
#pragma unroll
        for (int g = 1; g < 8; ++g) h = fmaxf(h, red[g][t]);
        hs[t] = h;
    }
    __syncthreads();

    if (t < 128) {
        float a1 = bh1[t];
        for (int i = 0; i < 128; ++i) a1 = fmaf(Wh1[t * 128 + i], hs[i], a1);
        h1s[t] = fmaxf(a1, 0.f);
    }
    __syncthreads();

    if (t < 64) {
        float a2 = bh2[t];
        for (int i = 0; i < 128; ++i) a2 = fmaf(Wh2[t * 128 + i], h1s[i], a2);
        h2s[t] = fmaxf(a2, 0.f);
    }
    __syncthreads();

    if (t < 32) {
        float a3 = bh3[t];
        for (int i = 0; i < 64; ++i) a3 = fmaf(Wh3[t * 64 + i], h2s[i], a3);
        h3s[t] = fmaxf(a3, 0.f);
    }
    __syncthreads();

    if (t == 0) {
        float a4 = bh4[0];
        for (int i = 0; i < 32; ++i) a4 = fmaf(Wh4[i], h3s[i], a4);
        out[b] = a4;
    }
}

// ---------------------------------------------------------------------------
extern "C" void kernel_launch(void* const* d_in, const int* in_sizes, int n_in,
                              void* d_out, int out_size, void* d_ws, size_t ws_size,
                              hipStream_t stream)
{
    const float* x    = (const float*)d_in[0];
    const int*   idx  = (const int*)d_in[1];
    const float* Wenc = (const float*)d_in[2];
    const float* benc = (const float*)d_in[3];
    const float* W1   = (const float*)d_in[4];
    const float* b1   = (const float*)d_in[5];
    const float* W2   = (const float*)d_in[6];
    const float* b2   = (const float*)d_in[7];
    const float* W3   = (const float*)d_in[8];
    const float* b3   = (const float*)d_in[9];
    const float* Wh1  = (const float*)d_in[10];
    const float* bh1  = (const float*)d_in[11];
    const float* Wh2  = (const float*)d_in[12];
    const float* bh2  = (const float*)d_in[13];
    const float* Wh3  = (const float*)d_in[14];
    const float* bh3  = (const float*)d_in[15];
    const float* Wh4  = (const float*)d_in[16];
    const float* bh4  = (const float*)d_in[17];
    float* out = (float*)d_out;

    char* ws = (char*)d_ws;
    // workspace layout (bytes)
    double* stats = (double*)ws;                          // 3 x B x {sum,sumsq}
    _Float16* w1h = (_Float16*)(ws + 8192);               // 512*384*2   = 393216
    _Float16* w1l = (_Float16*)(ws + 401408);
    _Float16* w2h = (_Float16*)(ws + 794624);             // 256*1536*2  = 786432
    _Float16* w2l = (_Float16*)(ws + 1581056);
    _Float16* w3h = (_Float16*)(ws + 2367488);            // 128*768*2   = 196608
    _Float16* w3l = (_Float16*)(ws + 2564096);
    _Float16* wEh = (_Float16*)(ws + 2760704);            // 128*320*2   = 81920
    _Float16* wEl = (_Float16*)(ws + 2842624);
    // f16 tree buffers: region A = max(t0, t2) = 67.2 MB; B = max(t1, t3)
    const size_t offA = 2924544;
    const size_t offB = offA + (size_t)B_ * MM_ * C2_ * sizeof(_Float16); // +67,174,400
    _Float16* t0 = (_Float16*)(ws + offA);                // (B,1025,128) padded
    _Float16* t1 = (_Float16*)(ws + offB);
    _Float16* t2 = (_Float16*)(ws + offA);
    _Float16* t3 = (_Float16*)(ws + offB);

    hipMemsetAsync(stats, 0, 3 * B_ * 2 * sizeof(double), stream);

    wprep_kernel<CH0_, 128, C1_><<<dim3((C1_ * 384 + 255) / 256), dim3(256), 0, stream>>>(W1, w1h, w1l);
    wprep_kernel<C1_,  C1_, C2_><<<dim3((C2_ * 1536 + 255) / 256), dim3(256), 0, stream>>>(W2, w2h, w2l);
    wprep_kernel<C2_,  C2_, C3_><<<dim3((C3_ * 768 + 255) / 256), dim3(256), 0, stream>>>(W3, w3h, w3l);
    wprep_enc_kernel<<<dim3((128 * 320 + 255) / 256), dim3(256), 0, stream>>>(Wenc, wEh, wEl);

    enc_mfma_kernel<<<dim3(4 * B_), dim3(512), 0, stream>>>(x, wEh, wEl, benc, t0);

    conv_mfma_kernel<C0P_, C1_, 256, false><<<dim3(4 * 2 * B_), dim3(1024), 0, stream>>>(
        t0, idx, w1h, b1, nullptr, 1, stats + 0, t1);

    conv_mfma_kernel<C1_, C2_, 256, true><<<dim3(4 * 1 * B_), dim3(1024), 0, stream>>>(
        t1, idx, w2h, b2, stats + 0, C1_ * MM_, stats + 2 * B_, t2);

    conv_mfma_kernel<C2_, C3_, 128, true><<<dim3(4 * 1 * B_), dim3(1024), 0, stream>>>(
        t2, idx, w3h, b3, stats + 2 * B_, C2_ * MM_, stats + 4 * B_, t3);

    pool_head_kernel<<<dim3(B_), dim3(1024), 0, stream>>>(
        t3, stats + 4 * B_, Wh1, bh1, Wh2, bh2, Wh3, bh3, Wh4, bh4, out);
}

// Round 18
// 335.565 us; speedup vs baseline: 2.1512x; 1.0880x over previous
//
#include <hip/hip_runtime.h>
#include <hip/hip_bf16.h>
#include <math.h>

#define B_   128
#define FQ_  318
#define CH0_ 109
#define NN_  1024
#define MM_  1025
#define C1_  512
#define C2_  256
#define C3_  128
#define C0P_ 128   // t0 channel padding (109 -> 128)

typedef _Float16 f16x8 __attribute__((ext_vector_type(8)));
typedef float    f32x4 __attribute__((ext_vector_type(4)));

#define GLOAD_LDS16(g, l) __builtin_amdgcn_global_load_lds( \
    (const __attribute__((address_space(1))) void*)(g),     \
    (__attribute__((address_space(3))) void*)(l), 16, 0, 0)
#define GLOAD_LDS4(g, l) __builtin_amdgcn_global_load_lds(  \
    (const __attribute__((address_space(1))) void*)(g),     \
    (__attribute__((address_space(3))) void*)(l), 4, 0, 0)

// LDS rows of 32 f16 (64 B = 4 quads of 16 B), quad-XOR swizzle.
__device__ __forceinline__ int lds_qoff(int row, int q) {
    return row * 32 + (((q ^ ((row >> 1) & 3)) & 3) << 3);
}

// ---------------------------------------------------------------------------
// Weight prep (convs): W (C_OUT, C_IN, 3) -> k-major Wr[o][kk*C_IN_PAD + c],
// split fp32 into f16 hi + f16 lo (convs consume Wh only).
// ---------------------------------------------------------------------------
template <int C_IN, int C_IN_PAD, int C_OUT>
__global__ __launch_bounds__(256) void wprep_kernel(
    const float* __restrict__ W, _Float16* __restrict__ Wh, _Float16* __restrict__ Wl)
{
    constexpr int KP = 3 * C_IN_PAD;
    const int id = blockIdx.x * 256 + threadIdx.x;
    if (id >= C_OUT * KP) return;
    const int o = id / KP, k = id - o * KP;
    const int kk = k / C_IN_PAD, c = k - kk * C_IN_PAD;
    const float v = (c < C_IN) ? W[((size_t)o * C_IN + c) * 3 + kk] : 0.f;
    const _Float16 h = (_Float16)v;
    Wh[id] = h;
    Wl[id] = (_Float16)(v - (float)h);
}

// ---------------------------------------------------------------------------
// Weight prep (encoder): Wenc (109, 318) -> padded (128, 320) h/l f16.
// ---------------------------------------------------------------------------
__global__ __launch_bounds__(256) void wprep_enc_kernel(
    const float* __restrict__ We, _Float16* __restrict__ Wh, _Float16* __restrict__ Wl)
{
    const int id = blockIdx.x * 256 + threadIdx.x;
    if (id >= 128 * 320) return;
    const int c = id / 320, f = id - c * 320;
    const float v = (c < CH0_ && f < FQ_) ? We[(size_t)c * FQ_ + f] : 0.f;
    const _Float16 h = (_Float16)v;
    Wh[id] = h;
    Wl[id] = (_Float16)(v - (float)h);
}

// ---------------------------------------------------------------------------
// MFMA encoder, 2-term (A = f16, W = f16 h+l): t0[b,vm+1,c] = x @ We^T + benc.
// t0 stored f16 (A-lo dropped: t0 is rounded to f16 at store anyway).
// ---------------------------------------------------------------------------
__global__ __launch_bounds__(512, 2) void enc_mfma_kernel(
    const float* __restrict__ x,
    const _Float16* __restrict__ Weh, const _Float16* __restrict__ Wel,
    const float* __restrict__ benc, _Float16* __restrict__ t0)
{
    constexpr int MROW = 264;                 // XS row stride (dwords)
    constexpr int NCE  = 10;                  // K chunks
    __shared__ __align__(16) float    XS[2][32 * MROW];
    __shared__ __align__(16) _Float16 WhS[2][128 * 32];
    __shared__ __align__(16) _Float16 WlS[2][128 * 32];

    const int tid  = threadIdx.x;
    const int lane = tid & 63, wid = tid >> 6;
    const int wr = wid >> 1, wc = wid & 1;
    const int lrow = lane & 15, lkg = lane >> 4;

    const int nwg  = 4 * B_;
    const int cpx  = nwg >> 3;
    const int swz  = (blockIdx.x & 7) * cpx + (blockIdx.x >> 3);
    const int b    = swz >> 2;
    const int mt   = swz & 3;
    const int m_base = mt * 256;

    auto stageX = [&](int ch, int buf) {
        const int f0 = ch * 32;
#pragma unroll
        for (int s = 0; s < 4; ++s) {
            const int floc = wid * 4 + s;
            int f = f0 + floc;
            if (f > FQ_ - 1) f = FQ_ - 1;
            const float* src = x + ((size_t)b * FQ_ + f) * MM_ + 1 + m_base;
            float* dst = &XS[buf][floc * MROW];
#pragma unroll
            for (int u = 0; u < 4; ++u)
                GLOAD_LDS4(src + u * 64 + lane, dst + u * 64);
        }
    };

    auto stageWE = [&](int ch, int buf) {
        const int baseRow = wid * 16;
        const int row  = baseRow + (lane >> 2);
        const int qp   = lane & 3;
        const int qsrc = qp ^ ((row >> 1) & 3);
        const size_t goff = (size_t)row * 320 + ch * 32 + qsrc * 8;
        GLOAD_LDS16(Weh + goff, &WhS[buf][baseRow * 32]);
        GLOAD_LDS16(Wel + goff, &WlS[buf][baseRow * 32]);
    };

    f32x4 acc[4][4];
#pragma unroll
    for (int i = 0; i < 4; ++i)
#pragma unroll
        for (int j = 0; j < 4; ++j) acc[i][j] = (f32x4){0.f, 0.f, 0.f, 0.f};

    auto compute = [&](int buf) {
        f16x8 ah[4];
#pragma unroll
        for (int i = 0; i < 4; ++i) {
            const int mloc = wr * 64 + i * 16 + lrow;
            const float* rp = &XS[buf][(lkg * 8) * MROW + mloc];
            f16x8 vh;
#pragma unroll
            for (int j = 0; j < 8; ++j) vh[j] = (_Float16)rp[j * MROW];
            ah[i] = vh;
        }
        __builtin_amdgcn_s_setprio(1);
#pragma unroll
        for (int j = 0; j < 4; ++j) {
            const int cr  = wc * 64 + j * 16 + lrow;
            const int off = lds_qoff(cr, lkg);
            const f16x8 bh = *reinterpret_cast<const f16x8*>(&WhS[buf][off]);
            const f16x8 bl = *reinterpret_cast<const f16x8*>(&WlS[buf][off]);
#pragma unroll
            for (int i = 0; i < 4; ++i)
                acc[i][j] = __builtin_amdgcn_mfma_f32_16x16x32_f16(ah[i], bh, acc[i][j], 0, 0, 0);
#pragma unroll
            for (int i = 0; i < 4; ++i)
                acc[i][j] = __builtin_amdgcn_mfma_f32_16x16x32_f16(ah[i], bl, acc[i][j], 0, 0, 0);
        }
        __builtin_amdgcn_s_setprio(0);
    };

    stageX(0, 0);
    stageWE(0, 0);
    __syncthreads();
    for (int ch = 0; ch < NCE; ++ch) {
        const int buf = ch & 1;
        if (ch + 1 < NCE) {
            stageX(ch + 1, buf ^ 1);
            stageWE(ch + 1, buf ^ 1);
        }
        compute(buf);
        __syncthreads();
    }

    _Float16* outb = t0 + (size_t)b * MM_ * C0P_;
#pragma unroll
    for (int i = 0; i < 4; ++i) {
        const int vm = m_base + wr * 64 + i * 16 + lkg * 4;
#pragma unroll
        for (int j = 0; j < 4; ++j) {
            const int c = wc * 64 + j * 16 + lrow;
            const float bb = (c < CH0_) ? benc[c] : 0.f;
#pragma unroll
            for (int r = 0; r < 4; ++r) {
                const float v = (c < CH0_) ? (acc[i][j][r] + bb) : 0.f;
                outb[(size_t)(vm + r + 1) * C0P_ + c] = (_Float16)v;
            }
        }
    }
    if (mt == 0) {
        for (int c = tid; c < C0P_; c += 512) outb[c] = (_Float16)0.f;
    }
}

// ---------------------------------------------------------------------------
// MFMA gather-conv, plain f16 (A = f16, W = f16, f32 accum), f16 trees.
// FUSE_MAX (conv3): no tout stores; per-column raw max reduced to
// pmax[b][mt][C_OUT] (monotone norm lets pool use raw maxes). Stats kept.
// R17 loop otherwise: 1024 thr = 16 waves (4n x 4o), tile 256n x OTILE.
// ---------------------------------------------------------------------------
template <int C_IN_STRIDE, int C_OUT, int OTILE, bool NORM, bool FUSE_MAX>
__global__ __launch_bounds__(1024, 4) void conv_mfma_kernel(
    const _Float16* __restrict__ tin, const int* __restrict__ idx,
    const _Float16* __restrict__ Wh,
    const float* __restrict__ bias,
    const double* __restrict__ stats_in, const int prev_count,
    double* __restrict__ stats_out, _Float16* __restrict__ tout,
    float* __restrict__ pmax)
{
    constexpr int KP   = 3 * C_IN_STRIDE;
    constexpr int NC   = KP / 32;             // k-chunks
    constexpr int CPC  = C_IN_STRIDE / 32;    // chunks per child (pow2)
    constexpr int OTB  = C_OUT / OTILE;       // o-tiles
    constexpr int OF   = OTILE / 64;          // B frags per wave (o-dir)
    static_assert(KP % 32 == 0 && (CPC & (CPC - 1)) == 0, "bad pad");
    static_assert(OTILE == 128 || OTILE == 256, "otile");
    static_assert(!FUSE_MAX || OTILE == 128, "fuse needs single o-tile");

    __shared__ __align__(16) _Float16 GhS[2][256 * 32];
    __shared__ __align__(16) _Float16 WhS[2][OTILE * 32];
    __shared__ int idxs[768];
    __shared__ float s_norm[2];
    __shared__ double redS[16], redQ[16];

    const int tid = threadIdx.x;

    // XCD-aware bijective swizzle (nwg % 8 == 0 for all instantiations)
    const int nwg  = 4 * OTB * B_;
    const int cpx  = nwg >> 3;
    const int orig = blockIdx.x;
    const int swz  = (orig & 7) * cpx + (orig >> 3);
    const int b    = swz / (4 * OTB);
    const int rr   = swz - b * (4 * OTB);
    const int mt   = rr / OTB;
    const int ot   = rr - mt * OTB;
    const int n_base = mt * 256;
    const int o0     = ot * OTILE;

    if (tid < 768) {
        idxs[tid] = idx[(size_t)b * (3 * NN_) + n_base * 3 + tid];
    }
    if (NORM && tid == 0) {
        const double s = stats_in[2 * b], q = stats_in[2 * b + 1];
        const double meand = s / prev_count;
        const double var   = (q - s * s / prev_count) / (prev_count - 1);
        s_norm[0] = (float)meand;
        s_norm[1] = (float)(1.0 / (sqrt(var) + 1e-5));
    }
    __syncthreads();
    const float mean = NORM ? s_norm[0] : 0.f;
    const float inv  = NORM ? s_norm[1] : 1.f;

    const _Float16* tb = tin + (size_t)b * MM_ * C_IN_STRIDE;
    const int gn = tid >> 2, gh = tid & 3;    // gather: 256 rows x 4 quads of 8
    const int lane = tid & 63, wid = tid >> 6;
    const int wr = wid >> 2, wc = wid & 3;    // wave grid 4n x 4o
    const int lrow = lane & 15, lkg = lane >> 4;

    f16x8 gv;

    auto load_chunk = [&](int ch) {           // 1 VMEM (16 B) per thread
        const int kk = ch / CPC;
        const int c0 = (ch & (CPC - 1)) << 5;
        const int r  = idxs[gn * 3 + kk];
        gv = *reinterpret_cast<const f16x8*>(tb + (size_t)r * C_IN_STRIDE + c0 + gh * 8);
    };

    // Wh staging, pre-swizzled source.
    auto stageW = [&](int ch, int buf) {
        if constexpr (OTILE == 256) {
            const int baseRow = wid * 16;
            const int row  = baseRow + (lane >> 2);
            const int qp   = lane & 3;
            const int qsrc = qp ^ ((row >> 1) & 3);
            const size_t goff = (size_t)(o0 + row) * KP + ch * 32 + qsrc * 8;
            GLOAD_LDS16(Wh + goff, &WhS[buf][baseRow * 32]);
        } else {
            if (wid < 8) {
                const int baseRow = wid * 16;
                const int row  = baseRow + (lane >> 2);
                const int qp   = lane & 3;
                const int qsrc = qp ^ ((row >> 1) & 3);
                const size_t goff = (size_t)(o0 + row) * KP + ch * 32 + qsrc * 8;
                GLOAD_LDS16(Wh + goff, &WhS[buf][baseRow * 32]);
            }
        }
    };

    auto store_chunk = [&](int buf) {
        const int off = lds_qoff(gn, gh);
        if constexpr (!NORM) {
            *reinterpret_cast<f16x8*>(&GhS[buf][off]) = gv;   // pure byte move
        } else {
            f16x8 vh;
#pragma unroll
            for (int e = 0; e < 8; ++e) {
                float v = (float)gv[e];
                v = fmaxf(0.f, v - mean);     // inv folded into epilogue
                vh[e] = (_Float16)v;
            }
            *reinterpret_cast<f16x8*>(&GhS[buf][off]) = vh;
        }
    };

    f32x4 acc[4][OF];
#pragma unroll
    for (int i = 0; i < 4; ++i)
#pragma unroll
        for (int j = 0; j < OF; ++j) acc[i][j] = (f32x4){0.f, 0.f, 0.f, 0.f};

    auto compute_chunk = [&](int buf) {
        f16x8 ah[4];
#pragma unroll
        for (int f = 0; f < 4; ++f) {
            const int ar  = wr * 64 + f * 16 + lrow;
            const int off = lds_qoff(ar, lkg);
            ah[f] = *reinterpret_cast<const f16x8*>(&GhS[buf][off]);
        }
        __builtin_amdgcn_s_setprio(1);
#pragma unroll
        for (int j = 0; j < OF; ++j) {
            const int br  = wc * (OTILE / 4) + j * 16 + lrow;
            const int off = lds_qoff(br, lkg);
            const f16x8 bh = *reinterpret_cast<const f16x8*>(&WhS[buf][off]);
#pragma unroll
            for (int i = 0; i < 4; ++i)
                acc[i][j] = __builtin_amdgcn_mfma_f32_16x16x32_f16(ah[i], bh, acc[i][j], 0, 0, 0);
        }
        __builtin_amdgcn_s_setprio(0);
    };

    // pipeline: dbuf LDS, one barrier per chunk (R8/R12-verified loop)
    stageW(0, 0);
    load_chunk(0);
    store_chunk(0);
    __syncthreads();
    for (int ch = 0; ch < NC; ++ch) {
        const int buf = ch & 1;
        if (ch + 1 < NC) {
            stageW(ch + 1, buf ^ 1);     // Wh DMA into other buffer
            load_chunk(ch + 1);          // A gather -> regs (latency under MFMA)
        }
        compute_chunk(buf);
        if (ch + 1 < NC) store_chunk(buf ^ 1);  // other buffer: no hazard
        __syncthreads();
    }

    // epilogue: scale by inv, add bias; stats on f32; store f16 OR fused max
    float bv[OF];
#pragma unroll
    for (int j = 0; j < OF; ++j) bv[j] = bias[o0 + wc * (OTILE / 4) + j * 16 + lrow];

    double s = 0.0, q = 0.0;
    float cm[OF];
#pragma unroll
    for (int j = 0; j < OF; ++j) cm[j] = -3.0e38f;

    _Float16* outb = tout + (size_t)b * MM_ * C_OUT;
#pragma unroll
    for (int i = 0; i < 4; ++i) {
        const int nrow = n_base + wr * 64 + i * 16 + lkg * 4;
#pragma unroll
        for (int j = 0; j < OF; ++j) {
            const int o = o0 + wc * (OTILE / 4) + j * 16 + lrow;
#pragma unroll
            for (int r = 0; r < 4; ++r) {
                const float v = fmaf(acc[i][j][r], inv, bv[j]);
                s += (double)v;
                q += (double)v * (double)v;
                if constexpr (FUSE_MAX) cm[j] = fmaxf(cm[j], v);
                else outb[(size_t)(nrow + r + 1) * C_OUT + o] = (_Float16)v;
            }
        }
    }
    if constexpr (!FUSE_MAX) {
        if (mt == 0) {
            for (int o = tid; o < OTILE; o += 1024) outb[o0 + o] = (_Float16)0.f;
        }
    }

    if constexpr (FUSE_MAX) {
        __shared__ float pmS[16][32];
#pragma unroll
        for (int j = 0; j < OF; ++j) {
            cm[j] = fmaxf(cm[j], __shfl_xor(cm[j], 16));
            cm[j] = fmaxf(cm[j], __shfl_xor(cm[j], 32));
        }
        if (lane < 16) {
            pmS[wid][lane]      = cm[0];
            pmS[wid][16 + lane] = cm[1];
        }
        __syncthreads();
        if (tid < 128) {
            const int o = tid, pwc = o >> 5, rem = o & 31;
            float m = pmS[0 * 4 + pwc][rem];
#pragma unroll
            for (int w2 = 1; w2 < 4; ++w2) m = fmaxf(m, pmS[w2 * 4 + pwc][rem]);
            pmax[((size_t)b * 4 + mt) * 128 + o] = m;
        }
    }

#pragma unroll
    for (int off = 32; off > 0; off >>= 1) {
        s += __shfl_down(s, off);
        q += __shfl_down(q, off);
    }
    if (lane == 0) { redS[wid] = s; redQ[wid] = q; }
    __syncthreads();
    if (tid == 0) {
        double ts = 0.0, tq = 0.0;
#pragma unroll
        for (int w = 0; w < 16; ++w) { ts += redS[w]; tq += redQ[w]; }
        atomicAdd(&stats_out[2 * b], ts);
        atomicAdd(&stats_out[2 * b + 1], tq);
    }
}

// ---------------------------------------------------------------------------
// Head: normalize partial maxes (monotone => max commutes with norm), MLP.
// 128 threads per batch.
// ---------------------------------------------------------------------------
__global__ __launch_bounds__(128) void pool_head_kernel(
    const float* __restrict__ pmax, const double* __restrict__ stats3,
    const float* __restrict__ Wh1, const float* __restrict__ bh1,
    const float* __restrict__ Wh2, const float* __restrict__ bh2,
    const float* __restrict__ Wh3, const float* __restrict__ bh3,
    const float* __restrict__ Wh4, const float* __restrict__ bh4,
    float* __restrict__ out)
{
    __shared__ float hs[128], h1s[128], h2s[64], h3s[32];
    const int b = blockIdx.x, t = threadIdx.x;

    const double ssum = stats3[2 * b], ssq = stats3[2 * b + 1];
    const double cnt  = (double)C3_ * (double)MM_;
    const double meand = ssum / cnt;
    const double var   = (ssq - ssum * ssum / cnt) / (cnt - 1.0);
    const float mean = (float)meand;
    const float inv  = (float)(1.0 / (sqrt(var) + 1e-5));

    float m = 0.f;                            // null-slot row: raw value 0
#pragma unroll
    for (int mt = 0; mt < 4; ++mt)
        m = fmaxf(m, pmax[((size_t)b * 4 + mt) * 128 + t]);
    hs[t] = fmaxf(0.f, (m - mean) * inv);
    __syncthreads();

    float a1 = bh1[t];
    for (int i = 0; i < 128; ++i) a1 = fmaf(Wh1[t * 128 + i], hs[i], a1);
    h1s[t] = fmaxf(a1, 0.f);
    __syncthreads();

    if (t < 64) {
        float a2 = bh2[t];
        for (int i = 0; i < 128; ++i) a2 = fmaf(Wh2[t * 128 + i], h1s[i], a2);
        h2s[t] = fmaxf(a2, 0.f);
    }
    __syncthreads();

    if (t < 32) {
        float a3 = bh3[t];
        for (int i = 0; i < 64; ++i) a3 = fmaf(Wh3[t * 64 + i], h2s[i], a3);
        h3s[t] = fmaxf(a3, 0.f);
    }
    __syncthreads();

    if (t == 0) {
        float a4 = bh4[0];
        for (int i = 0; i < 32; ++i) a4 = fmaf(Wh4[i], h3s[i], a4);
        out[b] = a4;
    }
}

// ---------------------------------------------------------------------------
extern "C" void kernel_launch(void* const* d_in, const int* in_sizes, int n_in,
                              void* d_out, int out_size, void* d_ws, size_t ws_size,
                              hipStream_t stream)
{
    const float* x    = (const float*)d_in[0];
    const int*   idx  = (const int*)d_in[1];
    const float* Wenc = (const float*)d_in[2];
    const float* benc = (const float*)d_in[3];
    const float* W1   = (const float*)d_in[4];
    const float* b1   = (const float*)d_in[5];
    const float* W2   = (const float*)d_in[6];
    const float* b2   = (const float*)d_in[7];
    const float* W3   = (const float*)d_in[8];
    const float* b3   = (const float*)d_in[9];
    const float* Wh1  = (const float*)d_in[10];
    const float* bh1  = (const float*)d_in[11];
    const float* Wh2  = (const float*)d_in[12];
    const float* bh2  = (const float*)d_in[13];
    const float* Wh3  = (const float*)d_in[14];
    const float* bh3  = (const float*)d_in[15];
    const float* Wh4  = (const float*)d_in[16];
    const float* bh4  = (const float*)d_in[17];
    float* out = (float*)d_out;

    char* ws = (char*)d_ws;
    // workspace layout (bytes)
    double* stats = (double*)ws;                          // 3 x B x {sum,sumsq}
    _Float16* w1h = (_Float16*)(ws + 8192);               // 512*384*2   = 393216
    _Float16* w1l = (_Float16*)(ws + 401408);
    _Float16* w2h = (_Float16*)(ws + 794624);             // 256*1536*2  = 786432
    _Float16* w2l = (_Float16*)(ws + 1581056);
    _Float16* w3h = (_Float16*)(ws + 2367488);            // 128*768*2   = 196608
    _Float16* w3l = (_Float16*)(ws + 2564096);
    _Float16* wEh = (_Float16*)(ws + 2760704);            // 128*320*2   = 81920
    _Float16* wEl = (_Float16*)(ws + 2842624);
    float*    pmax = (float*)(ws + 2924544);              // B*4*128*4   = 262144
    const size_t offA = 3186688;                          // t0 / t2 (f16)
    const size_t offB = offA + (size_t)B_ * MM_ * C2_ * sizeof(_Float16);
    _Float16* t0 = (_Float16*)(ws + offA);                // (B,1025,128) padded
    _Float16* t1 = (_Float16*)(ws + offB);
    _Float16* t2 = (_Float16*)(ws + offA);

    hipMemsetAsync(stats, 0, 3 * B_ * 2 * sizeof(double), stream);

    wprep_kernel<CH0_, 128, C1_><<<dim3((C1_ * 384 + 255) / 256), dim3(256), 0, stream>>>(W1, w1h, w1l);
    wprep_kernel<C1_,  C1_, C2_><<<dim3((C2_ * 1536 + 255) / 256), dim3(256), 0, stream>>>(W2, w2h, w2l);
    wprep_kernel<C2_,  C2_, C3_><<<dim3((C3_ * 768 + 255) / 256), dim3(256), 0, stream>>>(W3, w3h, w3l);
    wprep_enc_kernel<<<dim3((128 * 320 + 255) / 256), dim3(256), 0, stream>>>(Wenc, wEh, wEl);

    enc_mfma_kernel<<<dim3(4 * B_), dim3(512), 0, stream>>>(x, wEh, wEl, benc, t0);

    conv_mfma_kernel<C0P_, C1_, 256, false, false><<<dim3(4 * 2 * B_), dim3(1024), 0, stream>>>(
        t0, idx, w1h, b1, nullptr, 1, stats + 0, t1, nullptr);

    conv_mfma_kernel<C1_, C2_, 256, true, false><<<dim3(4 * 1 * B_), dim3(1024), 0, stream>>>(
        t1, idx, w2h, b2, stats + 0, C1_ * MM_, stats + 2 * B_, t2, nullptr);

    conv_mfma_kernel<C2_, C3_, 128, true, true><<<dim3(4 * 1 * B_), dim3(1024), 0, stream>>>(
        t2, idx, w3h, b3, stats + 2 * B_, C2_ * MM_, stats + 4 * B_, nullptr, pmax);

    pool_head_kernel<<<dim3(B_), dim3(128), 0, stream>>>(
        pmax, stats + 4 * B_, Wh1, bh1, Wh2, bh2, Wh3, bh3, Wh4, bh4, out);
}

// Round 19
// 335.019 us; speedup vs baseline: 2.1547x; 1.0016x over previous
//
#include <hip/hip_runtime.h>
#include <hip/hip_bf16.h>
#include <math.h>

#define B_   128
#define FQ_  318
#define CH0_ 109
#define NN_  1024
#define MM_  1025
#define C1_  512
#define C2_  256
#define C3_  128
#define C0P_ 128   // t0 channel padding (109 -> 128)

typedef _Float16 f16x8 __attribute__((ext_vector_type(8)));
typedef float    f32x4 __attribute__((ext_vector_type(4)));

#define GLOAD_LDS16(g, l) __builtin_amdgcn_global_load_lds( \
    (const __attribute__((address_space(1))) void*)(g),     \
    (__attribute__((address_space(3))) void*)(l), 16, 0, 0)
#define GLOAD_LDS4(g, l) __builtin_amdgcn_global_load_lds(  \
    (const __attribute__((address_space(1))) void*)(g),     \
    (__attribute__((address_space(3))) void*)(l), 4, 0, 0)

// LDS rows of 32 f16 (64 B = 4 quads of 16 B), quad-XOR swizzle.
__device__ __forceinline__ int lds_qoff(int row, int q) {
    return row * 32 + (((q ^ ((row >> 1) & 3)) & 3) << 3);
}

// ---------------------------------------------------------------------------
// Weight prep (convs): W (C_OUT, C_IN, 3) -> k-major Wr[o][kk*C_IN_PAD + c],
// split fp32 into f16 hi + f16 lo (convs consume Wh only).
// ---------------------------------------------------------------------------
template <int C_IN, int C_IN_PAD, int C_OUT>
__global__ __launch_bounds__(256) void wprep_kernel(
    const float* __restrict__ W, _Float16* __restrict__ Wh, _Float16* __restrict__ Wl)
{
    constexpr int KP = 3 * C_IN_PAD;
    const int id = blockIdx.x * 256 + threadIdx.x;
    if (id >= C_OUT * KP) return;
    const int o = id / KP, k = id - o * KP;
    const int kk = k / C_IN_PAD, c = k - kk * C_IN_PAD;
    const float v = (c < C_IN) ? W[((size_t)o * C_IN + c) * 3 + kk] : 0.f;
    const _Float16 h = (_Float16)v;
    Wh[id] = h;
    Wl[id] = (_Float16)(v - (float)h);
}

// ---------------------------------------------------------------------------
// Weight prep (encoder): Wenc (109, 318) -> padded (128, 320) h/l f16.
// ---------------------------------------------------------------------------
__global__ __launch_bounds__(256) void wprep_enc_kernel(
    const float* __restrict__ We, _Float16* __restrict__ Wh, _Float16* __restrict__ Wl)
{
    const int id = blockIdx.x * 256 + threadIdx.x;
    if (id >= 128 * 320) return;
    const int c = id / 320, f = id - c * 320;
    const float v = (c < CH0_ && f < FQ_) ? We[(size_t)c * FQ_ + f] : 0.f;
    const _Float16 h = (_Float16)v;
    Wh[id] = h;
    Wl[id] = (_Float16)(v - (float)h);
}

// ---------------------------------------------------------------------------
// MFMA encoder, 2-term (A = f16, W = f16 h+l): t0[b,vm+1,c] = x @ We^T + benc.
// ---------------------------------------------------------------------------
__global__ __launch_bounds__(512, 2) void enc_mfma_kernel(
    const float* __restrict__ x,
    const _Float16* __restrict__ Weh, const _Float16* __restrict__ Wel,
    const float* __restrict__ benc, _Float16* __restrict__ t0)
{
    constexpr int MROW = 264;                 // XS row stride (dwords)
    constexpr int NCE  = 10;                  // K chunks
    __shared__ __align__(16) float    XS[2][32 * MROW];
    __shared__ __align__(16) _Float16 WhS[2][128 * 32];
    __shared__ __align__(16) _Float16 WlS[2][128 * 32];

    const int tid  = threadIdx.x;
    const int lane = tid & 63, wid = tid >> 6;
    const int wr = wid >> 1, wc = wid & 1;
    const int lrow = lane & 15, lkg = lane >> 4;

    const int nwg  = 4 * B_;
    const int cpx  = nwg >> 3;
    const int swz  = (blockIdx.x & 7) * cpx + (blockIdx.x >> 3);
    const int b    = swz >> 2;
    const int mt   = swz & 3;
    const int m_base = mt * 256;

    auto stageX = [&](int ch, int buf) {
        const int f0 = ch * 32;
#pragma unroll
        for (int s = 0; s < 4; ++s) {
            const int floc = wid * 4 + s;
            int f = f0 + floc;
            if (f > FQ_ - 1) f = FQ_ - 1;
            const float* src = x + ((size_t)b * FQ_ + f) * MM_ + 1 + m_base;
            float* dst = &XS[buf][floc * MROW];
#pragma unroll
            for (int u = 0; u < 4; ++u)
                GLOAD_LDS4(src + u * 64 + lane, dst + u * 64);
        }
    };

    auto stageWE = [&](int ch, int buf) {
        const int baseRow = wid * 16;
        const int row  = baseRow + (lane >> 2);
        const int qp   = lane & 3;
        const int qsrc = qp ^ ((row >> 1) & 3);
        const size_t goff = (size_t)row * 320 + ch * 32 + qsrc * 8;
        GLOAD_LDS16(Weh + goff, &WhS[buf][baseRow * 32]);
        GLOAD_LDS16(Wel + goff, &WlS[buf][baseRow * 32]);
    };

    f32x4 acc[4][4];
#pragma unroll
    for (int i = 0; i < 4; ++i)
#pragma unroll
        for (int j = 0; j < 4; ++j) acc[i][j] = (f32x4){0.f, 0.f, 0.f, 0.f};

    auto compute = [&](int buf) {
        f16x8 ah[4];
#pragma unroll
        for (int i = 0; i < 4; ++i) {
            const int mloc = wr * 64 + i * 16 + lrow;
            const float* rp = &XS[buf][(lkg * 8) * MROW + mloc];
            f16x8 vh;
#pragma unroll
            for (int j = 0; j < 8; ++j) vh[j] = (_Float16)rp[j * MROW];
            ah[i] = vh;
        }
        __builtin_amdgcn_s_setprio(1);
#pragma unroll
        for (int j = 0; j < 4; ++j) {
            const int cr  = wc * 64 + j * 16 + lrow;
            const int off = lds_qoff(cr, lkg);
            const f16x8 bh = *reinterpret_cast<const f16x8*>(&WhS[buf][off]);
            const f16x8 bl = *reinterpret_cast<const f16x8*>(&WlS[buf][off]);
#pragma unroll
            for (int i = 0; i < 4; ++i)
                acc[i][j] = __builtin_amdgcn_mfma_f32_16x16x32_f16(ah[i], bh, acc[i][j], 0, 0, 0);
#pragma unroll
            for (int i = 0; i < 4; ++i)
                acc[i][j] = __builtin_amdgcn_mfma_f32_16x16x32_f16(ah[i], bl, acc[i][j], 0, 0, 0);
        }
        __builtin_amdgcn_s_setprio(0);
    };

    stageX(0, 0);
    stageWE(0, 0);
    __syncthreads();
    for (int ch = 0; ch < NCE; ++ch) {
        const int buf = ch & 1;
        if (ch + 1 < NCE) {
            stageX(ch + 1, buf ^ 1);
            stageWE(ch + 1, buf ^ 1);
        }
        compute(buf);
        __syncthreads();
    }

    _Float16* outb = t0 + (size_t)b * MM_ * C0P_;
#pragma unroll
    for (int i = 0; i < 4; ++i) {
        const int vm = m_base + wr * 64 + i * 16 + lkg * 4;
#pragma unroll
        for (int j = 0; j < 4; ++j) {
            const int c = wc * 64 + j * 16 + lrow;
            const float bb = (c < CH0_) ? benc[c] : 0.f;
#pragma unroll
            for (int r = 0; r < 4; ++r) {
                const float v = (c < CH0_) ? (acc[i][j][r] + bb) : 0.f;
                outb[(size_t)(vm + r + 1) * C0P_ + c] = (_Float16)v;
            }
        }
    }
    if (mt == 0) {
        for (int c = tid; c < C0P_; c += 512) outb[c] = (_Float16)0.f;
    }
}

// ---------------------------------------------------------------------------
// MFMA gather-conv, plain f16, f16 trees.
// NORM=false (conv1): A gathered DIRECTLY into LDS via global_load_lds —
//   per-lane gathered source with quad-XOR pre-applied (logical quad =
//   gh ^ ((gn>>1)&3)), linear LDS dest (wave base wid*512 + lane*16B ==
//   lds_qoff layout). No gv round trip, no ds_writes. Bit-identical bytes.
// NORM=true: R17 path (reg-stage, relu(v-mean) convert, ds_write).
// FUSE_MAX (conv3): per-column raw max -> pmax, no tout stores.
// ---------------------------------------------------------------------------
template <int C_IN_STRIDE, int C_OUT, int OTILE, bool NORM, bool FUSE_MAX>
__global__ __launch_bounds__(1024, 4) void conv_mfma_kernel(
    const _Float16* __restrict__ tin, const int* __restrict__ idx,
    const _Float16* __restrict__ Wh,
    const float* __restrict__ bias,
    const double* __restrict__ stats_in, const int prev_count,
    double* __restrict__ stats_out, _Float16* __restrict__ tout,
    float* __restrict__ pmax)
{
    constexpr int KP   = 3 * C_IN_STRIDE;
    constexpr int NC   = KP / 32;             // k-chunks
    constexpr int CPC  = C_IN_STRIDE / 32;    // chunks per child (pow2)
    constexpr int OTB  = C_OUT / OTILE;       // o-tiles
    constexpr int OF   = OTILE / 64;          // B frags per wave (o-dir)
    static_assert(KP % 32 == 0 && (CPC & (CPC - 1)) == 0, "bad pad");
    static_assert(OTILE == 128 || OTILE == 256, "otile");
    static_assert(!FUSE_MAX || OTILE == 128, "fuse needs single o-tile");

    __shared__ __align__(16) _Float16 GhS[2][256 * 32];
    __shared__ __align__(16) _Float16 WhS[2][OTILE * 32];
    __shared__ int idxs[768];
    __shared__ float s_norm[2];
    __shared__ double redS[16], redQ[16];

    const int tid = threadIdx.x;

    // XCD-aware bijective swizzle (nwg % 8 == 0 for all instantiations)
    const int nwg  = 4 * OTB * B_;
    const int cpx  = nwg >> 3;
    const int orig = blockIdx.x;
    const int swz  = (orig & 7) * cpx + (orig >> 3);
    const int b    = swz / (4 * OTB);
    const int rr   = swz - b * (4 * OTB);
    const int mt   = rr / OTB;
    const int ot   = rr - mt * OTB;
    const int n_base = mt * 256;
    const int o0     = ot * OTILE;

    if (tid < 768) {
        idxs[tid] = idx[(size_t)b * (3 * NN_) + n_base * 3 + tid];
    }
    if (NORM && tid == 0) {
        const double s = stats_in[2 * b], q = stats_in[2 * b + 1];
        const double meand = s / prev_count;
        const double var   = (q - s * s / prev_count) / (prev_count - 1);
        s_norm[0] = (float)meand;
        s_norm[1] = (float)(1.0 / (sqrt(var) + 1e-5));
    }
    __syncthreads();
    const float mean = NORM ? s_norm[0] : 0.f;
    const float inv  = NORM ? s_norm[1] : 1.f;

    const _Float16* tb = tin + (size_t)b * MM_ * C_IN_STRIDE;
    const int gn = tid >> 2, gh = tid & 3;    // gather: 256 rows x 4 quads of 8
    const int lane = tid & 63, wid = tid >> 6;
    const int wr = wid >> 2, wc = wid & 3;    // wave grid 4n x 4o
    const int lrow = lane & 15, lkg = lane >> 4;

    f16x8 gv;

    auto load_chunk = [&](int ch) {           // NORM path: 16 B gather -> regs
        const int kk = ch / CPC;
        const int c0 = (ch & (CPC - 1)) << 5;
        const int r  = idxs[gn * 3 + kk];
        gv = *reinterpret_cast<const f16x8*>(tb + (size_t)r * C_IN_STRIDE + c0 + gh * 8);
    };

    // Direct gather -> LDS DMA (NORM=false only): per-lane pre-swizzled source,
    // linear LDS dest (wave-uniform base + lane*16B).
    auto stageG = [&](int ch, int buf) {
        const int kk = ch / CPC;
        const int c0 = (ch & (CPC - 1)) << 5;
        const int r  = idxs[gn * 3 + kk];
        const int qlog = gh ^ ((gn >> 1) & 3);
        const _Float16* src = tb + (size_t)r * C_IN_STRIDE + c0 + (qlog << 3);
        GLOAD_LDS16(src, &GhS[buf][wid << 9]);
    };

    // Wh staging, pre-swizzled source.
    auto stageW = [&](int ch, int buf) {
        if constexpr (OTILE == 256) {
            const int baseRow = wid * 16;
            const int row  = baseRow + (lane >> 2);
            const int qp   = lane & 3;
            const int qsrc = qp ^ ((row >> 1) & 3);
            const size_t goff = (size_t)(o0 + row) * KP + ch * 32 + qsrc * 8;
            GLOAD_LDS16(Wh + goff, &WhS[buf][baseRow * 32]);
        } else {
            if (wid < 8) {
                const int baseRow = wid * 16;
                const int row  = baseRow + (lane >> 2);
                const int qp   = lane & 3;
                const int qsrc = qp ^ ((row >> 1) & 3);
                const size_t goff = (size_t)(o0 + row) * KP + ch * 32 + qsrc * 8;
                GLOAD_LDS16(Wh + goff, &WhS[buf][baseRow * 32]);
            }
        }
    };

    auto store_chunk = [&](int buf) {         // NORM path only
        f16x8 vh;
#pragma unroll
        for (int e = 0; e < 8; ++e) {
            float v = (float)gv[e];
            v = fmaxf(0.f, v - mean);         // inv folded into epilogue
            vh[e] = (_Float16)v;
        }
        *reinterpret_cast<f16x8*>(&GhS[buf][lds_qoff(gn, gh)]) = vh;
    };

    f32x4 acc[4][OF];
#pragma unroll
    for (int i = 0; i < 4; ++i)
#pragma unroll
        for (int j = 0; j < OF; ++j) acc[i][j] = (f32x4){0.f, 0.f, 0.f, 0.f};

    auto compute_chunk = [&](int buf) {
        f16x8 ah[4];
#pragma unroll
        for (int f = 0; f < 4; ++f) {
            const int ar  = wr * 64 + f * 16 + lrow;
            const int off = lds_qoff(ar, lkg);
            ah[f] = *reinterpret_cast<const f16x8*>(&GhS[buf][off]);
        }
        __builtin_amdgcn_s_setprio(1);
#pragma unroll
        for (int j = 0; j < OF; ++j) {
            const int br  = wc * (OTILE / 4) + j * 16 + lrow;
            const int off = lds_qoff(br, lkg);
            const f16x8 bh = *reinterpret_cast<const f16x8*>(&WhS[buf][off]);
#pragma unroll
            for (int i = 0; i < 4; ++i)
                acc[i][j] = __builtin_amdgcn_mfma_f32_16x16x32_f16(ah[i], bh, acc[i][j], 0, 0, 0);
        }
        __builtin_amdgcn_s_setprio(0);
    };

    // pipeline: dbuf LDS, one barrier per chunk
    if constexpr (!NORM) {
        stageG(0, 0);
        stageW(0, 0);
        __syncthreads();
        for (int ch = 0; ch < NC; ++ch) {
            const int buf = ch & 1;
            if (ch + 1 < NC) {
                stageG(ch + 1, buf ^ 1);     // gather DMA into other buffer
                stageW(ch + 1, buf ^ 1);
            }
            compute_chunk(buf);
            __syncthreads();
        }
    } else {
        stageW(0, 0);
        load_chunk(0);
        store_chunk(0);
        __syncthreads();
        for (int ch = 0; ch < NC; ++ch) {
            const int buf = ch & 1;
            if (ch + 1 < NC) {
                stageW(ch + 1, buf ^ 1);
                load_chunk(ch + 1);
            }
            compute_chunk(buf);
            if (ch + 1 < NC) store_chunk(buf ^ 1);
            __syncthreads();
        }
    }

    // epilogue: scale by inv, add bias; stats on f32; store f16 OR fused max
    float bv[OF];
#pragma unroll
    for (int j = 0; j < OF; ++j) bv[j] = bias[o0 + wc * (OTILE / 4) + j * 16 + lrow];

    double s = 0.0, q = 0.0;
    float cm[OF];
#pragma unroll
    for (int j = 0; j < OF; ++j) cm[j] = -3.0e38f;

    _Float16* outb = tout + (size_t)b * MM_ * C_OUT;
#pragma unroll
    for (int i = 0; i < 4; ++i) {
        const int nrow = n_base + wr * 64 + i * 16 + lkg * 4;
#pragma unroll
        for (int j = 0; j < OF; ++j) {
            const int o = o0 + wc * (OTILE / 4) + j * 16 + lrow;
#pragma unroll
            for (int r = 0; r < 4; ++r) {
                const float v = fmaf(acc[i][j][r], inv, bv[j]);
                s += (double)v;
                q += (double)v * (double)v;
                if constexpr (FUSE_MAX) cm[j] = fmaxf(cm[j], v);
                else outb[(size_t)(nrow + r + 1) * C_OUT + o] = (_Float16)v;
            }
        }
    }
    if constexpr (!FUSE_MAX) {
        if (mt == 0) {
            for (int o = tid; o < OTILE; o += 1024) outb[o0 + o] = (_Float16)0.f;
        }
    }

    if constexpr (FUSE_MAX) {
        __shared__ float pmS[16][32];
#pragma unroll
        for (int j = 0; j < OF; ++j) {
            cm[j] = fmaxf(cm[j], __shfl_xor(cm[j], 16));
            cm[j] = fmaxf(cm[j], __shfl_xor(cm[j], 32));
        }
        if (lane < 16) {
            pmS[wid][lane]      = cm[0];
            pmS[wid][16 + lane] = cm[1];
        }
        __syncthreads();
        if (tid < 128) {
            const int o = tid, pwc = o >> 5, rem = o & 31;
            float m = pmS[0 * 4 + pwc][rem];
#pragma unroll
            for (int w2 = 1; w2 < 4; ++w2) m = fmaxf(m, pmS[w2 * 4 + pwc][rem]);
            pmax[((size_t)b * 4 + mt) * 128 + o] = m;
        }
    }

#pragma unroll
    for (int off = 32; off > 0; off >>= 1) {
        s += __shfl_down(s, off);
        q += __shfl_down(q, off);
    }
    if (lane == 0) { redS[wid] = s; redQ[wid] = q; }
    __syncthreads();
    if (tid == 0) {
        double ts = 0.0, tq = 0.0;
#pragma unroll
        for (int w = 0; w < 16; ++w) { ts += redS[w]; tq += redQ[w]; }
        atomicAdd(&stats_out[2 * b], ts);
        atomicAdd(&stats_out[2 * b + 1], tq);
    }
}

// ---------------------------------------------------------------------------
// Head: normalize partial maxes (monotone => max commutes with norm), MLP.
// ---------------------------------------------------------------------------
__global__ __launch_bounds__(128) void pool_head_kernel(
    const float* __restrict__ pmax, const double* __restrict__ stats3,
    const float* __restrict__ Wh1, const float* __restrict__ bh1,
    const float* __restrict__ Wh2, const float* __restrict__ bh2,
    const float* __restrict__ Wh3, const float* __restrict__ bh3,
    const float* __restrict__ Wh4, const float* __restrict__ bh4,
    float* __restrict__ out)
{
    __shared__ float hs[128], h1s[128], h2s[64], h3s[32];
    const int b = blockIdx.x, t = threadIdx.x;

    const double ssum = stats3[2 * b], ssq = stats3[2 * b + 1];
    const double cnt  = (double)C3_ * (double)MM_;
    const double meand = ssum / cnt;
    const double var   = (ssq - ssum * ssum / cnt) / (cnt - 1.0);
    const float mean = (float)meand;
    const float inv  = (float)(1.0 / (sqrt(var) + 1e-5));

    float m = 0.f;                            // null-slot row: raw value 0
#pragma unroll
    for (int mt = 0; mt < 4; ++mt)
        m = fmaxf(m, pmax[((size_t)b * 4 + mt) * 128 + t]);
    hs[t] = fmaxf(0.f, (m - mean) * inv);
    __syncthreads();

    float a1 = bh1[t];
    for (int i = 0; i < 128; ++i) a1 = fmaf(Wh1[t * 128 + i], hs[i], a1);
    h1s[t] = fmaxf(a1, 0.f);
    __syncthreads();

    if (t < 64) {
        float a2 = bh2[t];
        for (int i = 0; i < 128; ++i) a2 = fmaf(Wh2[t * 128 + i], h1s[i], a2);
        h2s[t] = fmaxf(a2, 0.f);
    }
    __syncthreads();

    if (t < 32) {
        float a3 = bh3[t];
        for (int i = 0; i < 64; ++i) a3 = fmaf(Wh3[t * 64 + i], h2s[i], a3);
        h3s[t] = fmaxf(a3, 0.f);
    }
    __syncthreads();

    if (t == 0) {
        float a4 = bh4[0];
        for (int i = 0; i < 32; ++i) a4 = fmaf(Wh4[i], h3s[i], a4);
        out[b] = a4;
    }
}

// ---------------------------------------------------------------------------
extern "C" void kernel_launch(void* const* d_in, const int* in_sizes, int n_in,
                              void* d_out, int out_size, void* d_ws, size_t ws_size,
                              hipStream_t stream)
{
    const float* x    = (const float*)d_in[0];
    const int*   idx  = (const int*)d_in[1];
    const float* Wenc = (const float*)d_in[2];
    const float* benc = (const float*)d_in[3];
    const float* W1   = (const float*)d_in[4];
    const float* b1   = (const float*)d_in[5];
    const float* W2   = (const float*)d_in[6];
    const float* b2   = (const float*)d_in[7];
    const float* W3   = (const float*)d_in[8];
    const float* b3   = (const float*)d_in[9];
    const float* Wh1  = (const float*)d_in[10];
    const float* bh1  = (const float*)d_in[11];
    const float* Wh2  = (const float*)d_in[12];
    const float* bh2  = (const float*)d_in[13];
    const float* Wh3  = (const float*)d_in[14];
    const float* bh3  = (const float*)d_in[15];
    const float* Wh4  = (const float*)d_in[16];
    const float* bh4  = (const float*)d_in[17];
    float* out = (float*)d_out;

    char* ws = (char*)d_ws;
    // workspace layout (bytes)
    double* stats = (double*)ws;                          // 3 x B x {sum,sumsq}
    _Float16* w1h = (_Float16*)(ws + 8192);               // 512*384*2   = 393216
    _Float16* w1l = (_Float16*)(ws + 401408);
    _Float16* w2h = (_Float16*)(ws + 794624);             // 256*1536*2  = 786432
    _Float16* w2l = (_Float16*)(ws + 1581056);
    _Float16* w3h = (_Float16*)(ws + 2367488);            // 128*768*2   = 196608
    _Float16* w3l = (_Float16*)(ws + 2564096);
    _Float16* wEh = (_Float16*)(ws + 2760704);            // 128*320*2   = 81920
    _Float16* wEl = (_Float16*)(ws + 2842624);
    float*    pmax = (float*)(ws + 2924544);              // B*4*128*4   = 262144
    const size_t offA = 3186688;                          // t0 / t2 (f16)
    const size_t offB = offA + (size_t)B_ * MM_ * C2_ * sizeof(_Float16);
    _Float16* t0 = (_Float16*)(ws + offA);                // (B,1025,128) padded
    _Float16* t1 = (_Float16*)(ws + offB);
    _Float16* t2 = (_Float16*)(ws + offA);

    hipMemsetAsync(stats, 0, 3 * B_ * 2 * sizeof(double), stream);

    wprep_kernel<CH0_, 128, C1_><<<dim3((C1_ * 384 + 255) / 256), dim3(256), 0, stream>>>(W1, w1h, w1l);
    wprep_kernel<C1_,  C1_, C2_><<<dim3((C2_ * 1536 + 255) / 256), dim3(256), 0, stream>>>(W2, w2h, w2l);
    wprep_kernel<C2_,  C2_, C3_><<<dim3((C3_ * 768 + 255) / 256), dim3(256), 0, stream>>>(W3, w3h, w3l);
    wprep_enc_kernel<<<dim3((128 * 320 + 255) / 256), dim3(256), 0, stream>>>(Wenc, wEh, wEl);

    enc_mfma_kernel<<<dim3(4 * B_), dim3(512), 0, stream>>>(x, wEh, wEl, benc, t0);

    conv_mfma_kernel<C0P_, C1_, 256, false, false><<<dim3(4 * 2 * B_), dim3(1024), 0, stream>>>(
        t0, idx, w1h, b1, nullptr, 1, stats + 0, t1, nullptr);

    conv_mfma_kernel<C1_, C2_, 256, true, false><<<dim3(4 * 1 * B_), dim3(1024), 0, stream>>>(
        t1, idx, w2h, b2, stats + 0, C1_ * MM_, stats + 2 * B_, t2, nullptr);

    conv_mfma_kernel<C2_, C3_, 128, true, true><<<dim3(4 * 1 * B_), dim3(1024), 0, stream>>>(
        t2, idx, w3h, b3, stats + 2 * B_, C2_ * MM_, stats + 4 * B_, nullptr, pmax);

    pool_head_kernel<<<dim3(B_), dim3(128), 0, stream>>>(
        pmax, stats + 4 * B_, Wh1, bh1, Wh2, bh2, Wh3, bh3, Wh4, bh4, out);
}